// Round 3
// baseline (743.243 us; speedup 1.0000x reference)
//
#include <hip/hip_runtime.h>
#include <hip/hip_bf16.h>
#include <math.h>

typedef unsigned short u16;
typedef unsigned int u32;
typedef _Float16 f16;
typedef _Float16 f16x8 __attribute__((ext_vector_type(8)));
typedef float f32x4 __attribute__((ext_vector_type(4)));

// ---------------- constants ----------------
#define BATCH 32
#define CIN   1024
#define COUT  512
#define NPOS  8192
#define K9    9216
#define KHALF 4608
#define TOPK  30
#define NROI  960
#define POOLN 7
#define IMG   256

// ---------------- ws layout (float units) ----------------
#define O_XP0  0ull
#define O_XP1  4194304ull
#define O_CH   8388608ull      // u16[8388608]
#define O_CL   12582912ull
#define O_WH   16777216ull     // u16[4718592]
#define O_WL   19136512ull
#define O_Z    21495808ull     // 512 u16 zeros
#define O_HW   21496064ull     // float[23040] head weights TRANSPOSED [a][c]
#define O_SC   21519104ull
#define O_RG   21592832ull
#define O_ROI  21887744ull
#define O_VAL  21891584ull
#define O_LAB  21892544ull
#define O_W1T  21893504ull     // float[262144] w1 transposed [c][o]
#define O_W2T  22155648ull     // float[65536]  w2 transposed [c][o]
#define WS_FLOATS 22221184ull
// overlays on XP0/XP1 region (used only after heads consumed XP0/XP1):
#define O_PO   0ull
#define O_NF   1474560ull
#define O_PS   1720320ull      // float[960][2][3] supcon partials

// async global->LDS, 16 bytes/lane, LDS dest = wave-uniform base + lane*16
__device__ __forceinline__ void gl_lds16(const void* g, void* l) {
    __builtin_amdgcn_global_load_lds(
        (const __attribute__((address_space(1))) u32*)g,
        (__attribute__((address_space(3))) u32*)l,
        16, 0, 0);
}

// ---------------- fp16 hi/lo split ----------------
__device__ inline void split16(float x, u16& h, u16& l) {
    f16 hv = (f16)x;
    f16 lv = (f16)(x - (float)hv);
    h = *(u16*)&hv;
    l = *(u16*)&lv;
}

// ---------------- fused prep ----------------
#define NB_CLIP 8192
#define NB_W    2048
#define NB_Z    1
#define NB_HW   90
#define NB_W1T  1024
#define NB_W2T  256
__global__ __launch_bounds__(256)
void convert_all(const float* __restrict__ clip, const float* __restrict__ conv_w,
                 const float* __restrict__ cls_w, const float* __restrict__ reg_w,
                 const float* __restrict__ w1, const float* __restrict__ w2,
                 u16* __restrict__ CH, u16* __restrict__ CL,
                 u16* __restrict__ WH, u16* __restrict__ WL,
                 u16* __restrict__ Z, float* __restrict__ HW,
                 float* __restrict__ w1T, float* __restrict__ w2T) {
    __shared__ float wsh[2304];
    int bid = blockIdx.x, t = threadIdx.x;
    if (bid < NB_CLIP) {
        int tid = bid * 256 + t;
        int c4  = (tid & 255) * 4;
        int pos = (tid >> 8) & 255;
        int b   = tid >> 16;
        float4 v = *(const float4*)(clip + ((size_t)(1 + pos) * 32 + b) * 1024 + c4);
        float xs[4] = {v.x, v.y, v.z, v.w};
        ushort4 hh, ll;
        u16* hp = (u16*)&hh; u16* lp = (u16*)&ll;
#pragma unroll
        for (int q = 0; q < 4; ++q) split16(xs[q], hp[q], lp[q]);
        size_t o = ((size_t)(b * 256 + pos)) * 1024 + c4;
        *(ushort4*)(CH + o) = hh;
        *(ushort4*)(CL + o) = ll;
    } else if (bid < NB_CLIP + NB_W) {
        int bid2 = bid - NB_CLIP;
        int o = bid2 >> 2, cblk = bid2 & 3;
        const float* src = conv_w + (size_t)o * K9 + cblk * 2304;
        for (int i = t; i < 2304; i += 256) wsh[i] = src[i];
        __syncthreads();
#pragma unroll
        for (int p = 0; p < 9; ++p) {
            float x = wsh[t * 9 + p];
            u16 h, l;
            split16(x, h, l);
            size_t o2 = (size_t)o * K9 + p * 1024 + cblk * 256 + t;
            WH[o2] = h; WL[o2] = l;
        }
    } else if (bid < NB_CLIP + NB_W + NB_Z) {
        Z[t] = 0; Z[256 + t] = 0;
    } else if (bid < NB_CLIP + NB_W + NB_Z + NB_HW) {
        // head weights, TRANSPOSED: HW[a*512 + c], a in [0,45), c in [0,512)
        int tid2 = (bid - NB_CLIP - NB_W - NB_Z) * 256 + t;
        if (tid2 < 45 * 512) {
            int a = tid2 >> 9, c = tid2 & 511;
            HW[tid2] = (a < 9) ? cls_w[a * 512 + c] : reg_w[(a - 9) * 512 + c];
        }
    } else if (bid < NB_CLIP + NB_W + NB_Z + NB_HW + NB_W1T) {
        int tid2 = (bid - NB_CLIP - NB_W - NB_Z - NB_HW) * 256 + t;
        int o = tid2 >> 10, c = tid2 & 1023;
        w1T[c * 256 + o] = w1[(size_t)o * 1024 + c];
    } else {
        int tid2 = (bid - NB_CLIP - NB_W - NB_Z - NB_HW - NB_W1T) * 256 + t;
        int o = tid2 >> 8, c = tid2 & 255;
        w2T[c * 256 + o] = w2[(size_t)o * 256 + c];
    }
}

// ---------------- MFMA conv GEMM (verified round-0 version: 128x128, 2 blocks/CU) ----------------
__global__ __launch_bounds__(256, 2)
void conv_mfma(const u16* __restrict__ CH, const u16* __restrict__ CL,
               const u16* __restrict__ WH, const u16* __restrict__ WL,
               const u16* __restrict__ ZS,
               float* __restrict__ XP0, float* __restrict__ XP1) {
    __shared__ __align__(16) u16 Ah[8192];
    __shared__ __align__(16) u16 Al[8192];
    __shared__ __align__(16) u16 Bh[8192];
    __shared__ __align__(16) u16 Bl[8192];

    const int t = threadIdx.x;
    const int gid = blockIdx.x;
    const int nb = gid >> 7;
    const int g  = gid & 127;
    const int mb = g >> 1;
    const int ks = g & 1;
    const int ksOff = ks * KHALF;
    float* __restrict__ XP = ks ? XP1 : XP0;

    const int wave = t >> 6, lane = t & 63;

    int qA[2], siA[2], sjA[2], bA[2];
    const u16* srcBh[2];
    const u16* srcBl[2];
#pragma unroll
    for (int j = 0; j < 2; ++j) {
        int r = wave * 32 + j * 16 + (lane >> 2);
        int s = lane & 3;
        int q = s ^ ((r >> 1) & 3);
        qA[j] = q;
        int m = mb * 128 + r;
        bA[j] = m >> 8;
        int ij = m & 255;
        siA[j] = ij >> 4; sjA[j] = ij & 15;
        int o = nb * 128 + r;
        srcBh[j] = WH + (size_t)o * K9 + q * 8;
        srcBl[j] = WL + (size_t)o * K9 + q * 8;
    }

    const int wm = wave >> 1, wn = wave & 1;
    const int l16 = lane & 15, quad = lane >> 4;
    int offA[4], offB[4];
#pragma unroll
    for (int q = 0; q < 4; ++q) {
        int ar = wm * 64 + q * 16 + l16;
        offA[q] = ar * 32 + ((quad ^ ((ar >> 1) & 3)) << 3);
        int br = wn * 64 + q * 16 + l16;
        offB[q] = br * 32 + ((quad ^ ((br >> 1) & 3)) << 3);
    }

    f32x4 acc[4][4];
#pragma unroll
    for (int r = 0; r < 4; ++r)
#pragma unroll
        for (int c = 0; c < 4; ++c) acc[r][c] = (f32x4){0.f, 0.f, 0.f, 0.f};

    auto issue = [&](int it, int buf) {
        const int kg = ksOff + it * 32;
        const int p = kg >> 10;
        const int cb = kg & 1023;
        const int di = p / 3, dj = p - di * 3;
        const int base = buf << 12;
#pragma unroll
        for (int j = 0; j < 2; ++j) {
            int ii = siA[j] + di - 1, jj = sjA[j] + dj - 1;
            bool ok = ((unsigned)ii < 16u) && ((unsigned)jj < 16u);
            size_t aoff = ok ? ((((size_t)bA[j] << 8) + (size_t)(ii * 16 + jj)) << 10) + cb + qA[j] * 8
                             : 0;
            const u16* gah = ok ? CH + aoff : ZS;
            const u16* gal = ok ? CL + aoff : ZS;
            int lb = base + wave * 1024 + j * 512;
            gl_lds16(gah,           &Ah[lb]);
            gl_lds16(gal,           &Al[lb]);
            gl_lds16(srcBh[j] + kg, &Bh[lb]);
            gl_lds16(srcBl[j] + kg, &Bl[lb]);
        }
    };

    issue(0, 0);
    for (int it = 0; it < 144; ++it) {
        const int cur = it & 1;
        __syncthreads();
        if (it + 1 < 144) issue(it + 1, cur ^ 1);

        const int fb = cur << 12;
        f16x8 fah[4], fal[4], fbh[4], fbl[4];
#pragma unroll
        for (int x = 0; x < 4; ++x) {
            fah[x] = *(const f16x8*)&Ah[fb + offA[x]];
            fal[x] = *(const f16x8*)&Al[fb + offA[x]];
            fbh[x] = *(const f16x8*)&Bh[fb + offB[x]];
            fbl[x] = *(const f16x8*)&Bl[fb + offB[x]];
        }
#pragma unroll
        for (int tm = 0; tm < 4; ++tm)
#pragma unroll
            for (int tn = 0; tn < 4; ++tn) {
                acc[tm][tn] = __builtin_amdgcn_mfma_f32_16x16x32_f16(fal[tm], fbh[tn], acc[tm][tn], 0, 0, 0);
                acc[tm][tn] = __builtin_amdgcn_mfma_f32_16x16x32_f16(fah[tm], fbl[tn], acc[tm][tn], 0, 0, 0);
                acc[tm][tn] = __builtin_amdgcn_mfma_f32_16x16x32_f16(fah[tm], fbh[tn], acc[tm][tn], 0, 0, 0);
            }
    }

#pragma unroll
    for (int tm = 0; tm < 4; ++tm) {
        int mbase = mb * 128 + wm * 64 + tm * 16 + quad * 4;
#pragma unroll
        for (int tn = 0; tn < 4; ++tn) {
            int o = nb * 128 + wn * 64 + tn * 16 + l16;
#pragma unroll
            for (int r = 0; r < 4; ++r)
                XP[(size_t)(mbase + r) * COUT + o] = acc[tm][tn][r];
        }
    }
}

// ---------------- heads: float4 xs staging + transposed-HW float4 dot ----------------
__global__ __launch_bounds__(64)
void heads_kernel(const float* __restrict__ XP0, const float* __restrict__ XP1,
                  const float* __restrict__ conv_b, const float* __restrict__ HW,
                  const float* __restrict__ cls_b, const float* __restrict__ reg_b,
                  float* __restrict__ scores, float* __restrict__ regs) {
    __shared__ float xs[512];
    int mm = blockIdx.x;
    int t = threadIdx.x;
    // stage x row: relu(XP0+XP1+conv_b), vectorized (128 float4 over 64 lanes)
    const float4* x0 = (const float4*)(XP0 + (size_t)mm * COUT);
    const float4* x1 = (const float4*)(XP1 + (size_t)mm * COUT);
    const float4* cb = (const float4*)conv_b;
#pragma unroll
    for (int q = 0; q < 2; ++q) {
        int i = t + 64 * q;
        float4 a = x0[i], b = x1[i], c = cb[i];
        float4 r;
        r.x = fmaxf(a.x + b.x + c.x, 0.f);
        r.y = fmaxf(a.y + b.y + c.y, 0.f);
        r.z = fmaxf(a.z + b.z + c.z, 0.f);
        r.w = fmaxf(a.w + b.w + c.w, 0.f);
        ((float4*)xs)[i] = r;
    }
    __syncthreads();
    if (t < 45) {
        // HW is transposed [a][c]: per-lane contiguous row -> float4 loads
        const float* hw = HW + t * 512;
        float acc = (t < 9) ? cls_b[t] : reg_b[t - 9];
#pragma unroll 4
        for (int c = 0; c < 512; c += 4) {
            float4 w4 = *(const float4*)(hw + c);
            acc = fmaf(xs[c + 0], w4.x, acc);
            acc = fmaf(xs[c + 1], w4.y, acc);
            acc = fmaf(xs[c + 2], w4.z, acc);
            acc = fmaf(xs[c + 3], w4.w, acc);
        }
        int b = mm >> 8, cell = mm & 255;
        if (t < 9) {
            scores[(size_t)b * 2304 + cell * 9 + t] = 1.f / (1.f + expf(-acc));
        } else {
            int ch = t - 9;
            regs[((size_t)b * 2304 + cell * 9 + (ch >> 2)) * 4 + (ch & 3)] = acc;
        }
    }
}

// ---------------- top-k + decode + NMS per image (unchanged) ----------------
__global__ __launch_bounds__(256)
void topk_nms(const float* __restrict__ scores, const float* __restrict__ regs,
              float* __restrict__ rois, float* __restrict__ valid) {
    __shared__ float sc[2304];
    __shared__ float wv[4];
    __shared__ int   wi[4];
    __shared__ int   sel[TOPK];
    __shared__ float bx[TOPK][4];
    __shared__ float iou[TOPK * TOPK];
    __shared__ float keepsh[TOPK];
    int b = blockIdx.x, t = threadIdx.x;
    for (int q = t; q < 2304; q += 256) sc[q] = scores[(size_t)b * 2304 + q];
    __syncthreads();

    for (int k = 0; k < TOPK; ++k) {
        float bv = -1e30f; int bi = 1 << 30;
#pragma unroll
        for (int q = 0; q < 9; ++q) {
            int idx = t * 9 + q;
            float v = sc[idx];
            if (v > bv || (v == bv && idx < bi)) { bv = v; bi = idx; }
        }
        for (int off = 32; off; off >>= 1) {
            float ov = __shfl_down(bv, off);
            int   oi = __shfl_down(bi, off);
            if (ov > bv || (ov == bv && oi < bi)) { bv = ov; bi = oi; }
        }
        int lane = t & 63, w = t >> 6;
        if (lane == 0) { wv[w] = bv; wi[w] = bi; }
        __syncthreads();
        if (t == 0) {
            float fv = wv[0]; int fi = wi[0];
            for (int q = 1; q < 4; ++q)
                if (wv[q] > fv || (wv[q] == fv && wi[q] < fi)) { fv = wv[q]; fi = wi[q]; }
            sel[k] = fi;
            sc[fi] = -1e38f;
        }
        __syncthreads();
    }

    if (t < TOPK) {
        int n = sel[t];
        int cell = n / 9, a = n % 9;
        int ci = cell >> 4, cj = cell & 15;
        int siid = a / 3, riid = a % 3;
        const double scl[3] = {8.0, 16.0, 32.0};
        const double rat[3] = {0.5, 1.0, 2.0};
        double s = scl[siid], r = rat[riid];
        double wD = s * sqrt(r), hD = s / sqrt(r);
        double xc = (cj + 0.5) * 16.0, yc = (ci + 0.5) * 16.0;
        float ax1 = (float)(xc - wD / 2), ay1 = (float)(yc - hD / 2);
        float ax2 = (float)(xc + wD / 2), ay2 = (float)(yc + hD / 2);
        float aw = ax2 - ax1, ah = ay2 - ay1;
        float ctrx = ax1 + 0.5f * aw, ctry = ay1 + 0.5f * ah;
        const float* rg = regs + ((size_t)b * 2304 + n) * 4;
        float cx = rg[0] * aw + ctrx;
        float cy = rg[1] * ah + ctry;
        float pw = expf(rg[2]) * aw;
        float ph = expf(rg[3]) * ah;
        float x1 = cx - 0.5f * pw, y1 = cy - 0.5f * ph;
        float x2 = cx + 0.5f * pw, y2 = cy + 0.5f * ph;
        x1 = fminf(fmaxf(x1, 0.f), 256.f);
        y1 = fminf(fmaxf(y1, 0.f), 256.f);
        x2 = fminf(fmaxf(x2, 0.f), 256.f);
        y2 = fminf(fmaxf(y2, 0.f), 256.f);
        if (x2 - x1 < 1.f) x2 = x1 + 1.f;
        if (y2 - y1 < 1.f) y2 = y1 + 1.f;
        bx[t][0] = x1; bx[t][1] = y1; bx[t][2] = x2; bx[t][3] = y2;
    }
    __syncthreads();
    if (t < TOPK * TOPK) {
        int ii = t / TOPK, jj = t % TOPK;
        float xi1 = bx[ii][0], yi1 = bx[ii][1], xi2 = bx[ii][2], yi2 = bx[ii][3];
        float xj1 = bx[jj][0], yj1 = bx[jj][1], xj2 = bx[jj][2], yj2 = bx[jj][3];
        float ai = (xi2 - xi1) * (yi2 - yi1), aj = (xj2 - xj1) * (yj2 - yj1);
        float iw = fmaxf(fminf(xi2, xj2) - fmaxf(xi1, xj1), 0.f);
        float ih = fmaxf(fminf(yi2, yj2) - fmaxf(yi1, yj1), 0.f);
        float inter = iw * ih;
        iou[t] = inter / (ai + aj - inter);
    }
    __syncthreads();
    if (t == 0) {
        bool keep[TOPK];
        for (int q = 0; q < TOPK; ++q) keep[q] = true;
        for (int iK = 0; iK < TOPK; ++iK) {
            if (!keep[iK]) continue;
            for (int jK = iK + 1; jK < TOPK; ++jK)
                if (keep[jK] && iou[iK * TOPK + jK] > 0.85f) keep[jK] = false;
        }
        for (int q = 0; q < TOPK; ++q) keepsh[q] = keep[q] ? 1.f : 0.f;
    }
    __syncthreads();
    if (t < TOPK) {
        int rr = b * TOPK + t;
        rois[rr * 4 + 0] = bx[t][0]; rois[rr * 4 + 1] = bx[t][1];
        rois[rr * 4 + 2] = bx[t][2]; rois[rr * 4 + 3] = bx[t][3];
        valid[rr] = keepsh[t];
    }
}

// ---------------- roi-align, image-sliced (unchanged) ----------------
__global__ __launch_bounds__(256)
void align_img(const float* __restrict__ clip, const float* __restrict__ rois,
               float* __restrict__ pooled) {
    __shared__ float slice[16384];   // 64 KB: [pos 0..255][ch 0..63]
    int bid = blockIdx.x;            // 0..511
    int b = bid >> 4, cg = bid & 15;
    int t = threadIdx.x;
    for (int idx = t; idx < 16384; idx += 256) {
        int p = idx >> 6, c = idx & 63;
        slice[idx] = clip[(size_t)(1 + p) * 32768 + (size_t)b * 1024 + cg * 64 + c];
    }
    __syncthreads();
    int wv = t >> 6;
    int ch = t & 63;
    for (int rp = 0; rp < 8; ++rp) {
        int rl = rp * 4 + wv;
        if (rl >= TOPK) continue;
        int r = b * TOPK + rl;
        float rx1 = rois[r * 4 + 0] * 0.0625f, ry1 = rois[r * 4 + 1] * 0.0625f;
        float rw = fmaxf(rois[r * 4 + 2] * 0.0625f - rx1, 1.f);
        float rh = fmaxf(rois[r * 4 + 3] * 0.0625f - ry1, 1.f);
        float sx = rw / (float)POOLN, sy = rh / (float)POOLN;
        float acc = 0.f;
        for (int py = 0; py < POOLN; ++py) {
            float Y = ry1 + ((float)py + 0.5f) * sy;
            for (int px = 0; px < POOLN; ++px) {
                float Xx = rx1 + ((float)px + 0.5f) * sx;
                bool ok = (Y > -1.f) && (Y < 16.f) && (Xx > -1.f) && (Xx < 16.f);
                if (!ok) continue;
                float Xc = fminf(fmaxf(Xx, 0.f), 15.f);
                float Yc = fminf(fmaxf(Y, 0.f), 15.f);
                int x0 = (int)floorf(Xc), y0 = (int)floorf(Yc);
                int x1i = min(x0 + 1, 15), y1i = min(y0 + 1, 15);
                float lx = Xc - (float)x0, ly = Yc - (float)y0;
                float hx = 1.f - lx, hy = 1.f - ly;
                float w00 = hy * hx, w01 = hy * lx, w10 = ly * hx, w11 = ly * lx;
                float f00 = slice[(y0 * 16 + x0) * 64 + ch];
                float f01 = slice[(y0 * 16 + x1i) * 64 + ch];
                float f10 = slice[(y1i * 16 + x0) * 64 + ch];
                float f11 = slice[(y1i * 16 + x1i) * 64 + ch];
                acc += w00 * f00 + w01 * f01 + w10 * f10 + w11 * f11;
            }
        }
        pooled[(size_t)r * 1024 + cg * 64 + ch] = acc / 49.f;
    }
}

// ---------------- roi labels (unchanged) ----------------
__global__ __launch_bounds__(256)
void labels_k(const float* __restrict__ gt, const float* __restrict__ rois,
              float* __restrict__ labels) {
    __shared__ float red[4];
    int r = blockIdx.x, t = threadIdx.x;
    int b = r / TOPK;
    int x1 = min(max((int)rois[r * 4 + 0], 0), 256);
    int y1 = min(max((int)rois[r * 4 + 1], 0), 256);
    int x2 = min(max((int)rois[r * 4 + 2], 0), 256);
    int y2 = min(max((int)rois[r * 4 + 3], 0), 256);
    int cnt = (x2 - x1) * (y2 - y1);
    float s = 0.f;
    if (cnt > 0) {
        const float* g = gt + (size_t)b * (IMG * IMG);
        for (int yy = y1; yy < y2; ++yy) {
            const float* row = g + yy * IMG;
            for (int xx = x1 + t; xx < x2; xx += 256) s += row[xx];
        }
    }
    for (int off = 32; off; off >>= 1) s += __shfl_down(s, off);
    if ((t & 63) == 0) red[t >> 6] = s;
    __syncthreads();
    if (t == 0) {
        float tot = red[0] + red[1] + red[2] + red[3];
        labels[r] = (cnt > 0 && 2.f * tot > (float)cnt) ? 1.f : 0.f;
    }
}

// ---------------- fused fc1(relu) -> fc2 -> normalize, 4 rois/block ----------------
__global__ __launch_bounds__(256)
void fc_norm(const float* __restrict__ pooled, const float* __restrict__ w1T,
             const float* __restrict__ b1, const float* __restrict__ w2T,
             const float* __restrict__ b2, float* __restrict__ nf) {
    __shared__ float rows[4][1024];
    __shared__ float hsh[4][256];
    __shared__ float red[4];
    int r0 = blockIdx.x * 4, t = threadIdx.x;
    for (int q = 0; q < 4; ++q)
        for (int c = t; c < 1024; c += 256)
            rows[q][c] = pooled[(size_t)(r0 + q) * 1024 + c];
    __syncthreads();
    {
        float bv = b1[t];
        float acc[4] = {bv, bv, bv, bv};
        for (int c = 0; c < 1024; ++c) {
            float wv = w1T[c * 256 + t];
#pragma unroll
            for (int q = 0; q < 4; ++q) acc[q] = fmaf(rows[q][c], wv, acc[q]);
        }
#pragma unroll
        for (int q = 0; q < 4; ++q) hsh[q][t] = fmaxf(acc[q], 0.f);
    }
    __syncthreads();
    float pr[4];
    {
        float bv = b2[t];
        float acc[4] = {bv, bv, bv, bv};
        for (int c = 0; c < 256; ++c) {
            float wv = w2T[c * 256 + t];
#pragma unroll
            for (int q = 0; q < 4; ++q) acc[q] = fmaf(hsh[q][c], wv, acc[q]);
        }
#pragma unroll
        for (int q = 0; q < 4; ++q) pr[q] = acc[q];
    }
    for (int q = 0; q < 4; ++q) {
        float v = pr[q];
        float ss = v * v;
        for (int off = 32; off; off >>= 1) ss += __shfl_down(ss, off);
        if ((t & 63) == 0) red[t >> 6] = ss;
        __syncthreads();
        float tot = red[0] + red[1] + red[2] + red[3];
        float denom = fmaxf(sqrtf(tot), 1e-12f);
        nf[(size_t)(r0 + q) * 256 + t] = v / denom;
        __syncthreads();
    }
}

// ---------------- supcon partials: block = (i, j-half), 1920 blocks ----------------
__global__ __launch_bounds__(256)
void supcon_half(const float* __restrict__ nf, const float* __restrict__ labels,
                 const float* __restrict__ valid, float* __restrict__ PS) {
    __shared__ float my[256];
    __shared__ float labs[NROI], vals[NROI];
    __shared__ float wsa[4], wsp[4];
    __shared__ int wnp[4];
    int bid = blockIdx.x, t = threadIdx.x;
    int i = bid >> 1, half = bid & 1;
    my[t] = nf[(size_t)i * 256 + t];
    for (int q = t; q < NROI; q += 256) { labs[q] = labels[q]; vals[q] = valid[q]; }
    __syncthreads();
    float vi = vals[i], li = labs[i];
    float sum_all = 0.f, sum_pos = 0.f;
    int np = 0;
    int w = t >> 6, lane = t & 63;
    float4 my4 = ((const float4*)my)[lane];
    int j0 = half * 480, j1 = j0 + 480;
    if (vi > 0.5f) {
        for (int j = j0 + w; j < j1; j += 4) {
            float4 v4 = ((const float4*)(nf + (size_t)j * 256))[lane];
            float p = my4.x * v4.x;
            p = fmaf(my4.y, v4.y, p);
            p = fmaf(my4.z, v4.z, p);
            p = fmaf(my4.w, v4.w, p);
#pragma unroll
            for (int off = 32; off; off >>= 1) p += __shfl_xor(p, off);
            if (j != i && vals[j] > 0.5f) {
                float e = expf(p / 0.07f);
                sum_all += e;
                if (labs[j] == li) { sum_pos += e; np++; }
            }
        }
    }
    if (lane == 0) { wsa[w] = sum_all; wsp[w] = sum_pos; wnp[w] = np; }
    __syncthreads();
    if (t == 0) {
        float sa = wsa[0] + wsa[1] + wsa[2] + wsa[3];
        float sp = wsp[0] + wsp[1] + wsp[2] + wsp[3];
        int tnp = wnp[0] + wnp[1] + wnp[2] + wnp[3];
        PS[(size_t)i * 6 + half * 3 + 0] = sa;
        PS[(size_t)i * 6 + half * 3 + 1] = sp;
        PS[(size_t)i * 6 + half * 3 + 2] = (float)tnp;
    }
}

// ---------------- final: combine halves, per-row loss, mean ----------------
__global__ __launch_bounds__(256)
void final_reduce2(const float* __restrict__ PS, const float* __restrict__ valid,
                   float* __restrict__ out) {
    __shared__ float rl[4], ra[4];
    int t = threadIdx.x;
    float sl = 0.f, sc = 0.f;
    for (int i = t; i < NROI; i += 256) {
        float sa = PS[(size_t)i * 6 + 0] + PS[(size_t)i * 6 + 3];
        float sp = PS[(size_t)i * 6 + 1] + PS[(size_t)i * 6 + 4];
        float np = PS[(size_t)i * 6 + 2] + PS[(size_t)i * 6 + 5];
        bool active = (valid[i] > 0.5f) && (np > 0.5f);
        float ratio = sp / (sa + 1e-12f);
        float l = -logf(ratio + 1e-12f);
        sl += active ? l : 0.f;
        sc += active ? 1.f : 0.f;
    }
    for (int off = 32; off; off >>= 1) { sl += __shfl_down(sl, off); sc += __shfl_down(sc, off); }
    if ((t & 63) == 0) { rl[t >> 6] = sl; ra[t >> 6] = sc; }
    __syncthreads();
    if (t == 0) {
        float L = rl[0] + rl[1] + rl[2] + rl[3];
        float A = ra[0] + ra[1] + ra[2] + ra[3];
        out[0] = (A > 0.f) ? (L / fmaxf(A, 1.f)) : 0.f;
    }
}

// ---------------- launch ----------------
extern "C" void kernel_launch(void* const* d_in, const int* in_sizes, int n_in,
                              void* d_out, int out_size, void* d_ws, size_t ws_size,
                              hipStream_t stream) {
    const float* clip   = (const float*)d_in[0];
    const float* gt     = (const float*)d_in[1];
    const float* conv_w = (const float*)d_in[2];
    const float* conv_b = (const float*)d_in[3];
    const float* cls_w  = (const float*)d_in[4];
    const float* cls_b  = (const float*)d_in[5];
    const float* reg_w  = (const float*)d_in[6];
    const float* reg_b  = (const float*)d_in[7];
    const float* w1     = (const float*)d_in[8];
    const float* b1     = (const float*)d_in[9];
    const float* w2     = (const float*)d_in[10];
    const float* b2     = (const float*)d_in[11];

    if (ws_size < WS_FLOATS * sizeof(float)) return;  // visible failure if ws too small

    float* ws  = (float*)d_ws;
    float* XP0 = ws + O_XP0;
    float* XP1 = ws + O_XP1;
    u16*   CH  = (u16*)(ws + O_CH);
    u16*   CL  = (u16*)(ws + O_CL);
    u16*   WHp = (u16*)(ws + O_WH);
    u16*   WLp = (u16*)(ws + O_WL);
    u16*   ZS  = (u16*)(ws + O_Z);
    float* HW  = ws + O_HW;
    float* SC  = ws + O_SC;
    float* RG  = ws + O_RG;
    float* ROI = ws + O_ROI;
    float* VAL = ws + O_VAL;
    float* LAB = ws + O_LAB;
    float* W1T = ws + O_W1T;
    float* W2T = ws + O_W2T;
    float* PO  = ws + O_PO;
    float* NF  = ws + O_NF;
    float* PS  = ws + O_PS;

    convert_all<<<NB_CLIP + NB_W + NB_Z + NB_HW + NB_W1T + NB_W2T, 256, 0, stream>>>(
        clip, conv_w, cls_w, reg_w, w1, w2, CH, CL, WHp, WLp, ZS, HW, W1T, W2T);
    conv_mfma<<<512, 256, 0, stream>>>(CH, CL, WHp, WLp, ZS, XP0, XP1);
    heads_kernel<<<NPOS, 64, 0, stream>>>(XP0, XP1, conv_b, HW, cls_b, reg_b, SC, RG);
    topk_nms<<<BATCH, 256, 0, stream>>>(SC, RG, ROI, VAL);
    align_img<<<512, 256, 0, stream>>>(clip, ROI, PO);
    labels_k<<<NROI, 256, 0, stream>>>(gt, ROI, LAB);
    fc_norm<<<NROI / 4, 256, 0, stream>>>(PO, W1T, b1, W2T, b2, NF);
    supcon_half<<<2 * NROI, 256, 0, stream>>>(NF, LAB, VAL, PS);
    final_reduce2<<<1, 256, 0, stream>>>(PS, VAL, (float*)d_out);
}

// Round 4
// 649.474 us; speedup vs baseline: 1.1444x; 1.1444x over previous
//
#include <hip/hip_runtime.h>
#include <hip/hip_bf16.h>
#include <math.h>

typedef unsigned short u16;
typedef unsigned int u32;
typedef _Float16 f16;
typedef _Float16 f16x8 __attribute__((ext_vector_type(8)));
typedef float f32x4 __attribute__((ext_vector_type(4)));

// ---------------- constants ----------------
#define BATCH 32
#define CIN   1024
#define COUT  512
#define NPOS  8192
#define K9    9216
#define KHALF 4608
#define TOPK  30
#define NROI  960
#define POOLN 7
#define IMG   256
#define SJT   15      // supcon j-tiles of 64 (960/64)

// ---------------- ws layout (float units) ----------------
#define O_XP0  0ull
#define O_XP1  4194304ull
#define O_CH   8388608ull      // u16[8388608]
#define O_CL   12582912ull
#define O_WH   16777216ull     // u16[4718592]
#define O_WL   19136512ull
#define O_Z    21495808ull     // 512 u16 zeros
#define O_HW   21496064ull     // float[23040] head weights [c][45]
#define O_SC   21519104ull
#define O_RG   21592832ull
#define O_ROI  21887744ull
#define O_VAL  21891584ull
#define O_LAB  21892544ull
#define O_W1T  21893504ull     // float[262144] w1 transposed [c][o]
#define O_W2T  22155648ull     // float[65536]  w2 transposed [c][o]
#define WS_FLOATS 22221184ull
// overlays on XP0/XP1 region (used only after heads consumed XP0/XP1):
#define O_PO   0ull
#define O_NF   1474560ull
#define O_PS   1720320ull      // float[960][SJT][3] supcon partials (43200 floats)

// async global->LDS, 16 bytes/lane, LDS dest = wave-uniform base + lane*16
__device__ __forceinline__ void gl_lds16(const void* g, void* l) {
    __builtin_amdgcn_global_load_lds(
        (const __attribute__((address_space(1))) u32*)g,
        (__attribute__((address_space(3))) u32*)l,
        16, 0, 0);
}

// ---------------- fp16 hi/lo split ----------------
__device__ inline void split16(float x, u16& h, u16& l) {
    f16 hv = (f16)x;
    f16 lv = (f16)(x - (float)hv);
    h = *(u16*)&hv;
    l = *(u16*)&lv;
}

// ---------------- fused prep (exact round-0 version) ----------------
#define NB_CLIP 8192
#define NB_W    2048
#define NB_Z    1
#define NB_HW   90
#define NB_W1T  1024
#define NB_W2T  256
__global__ __launch_bounds__(256)
void convert_all(const float* __restrict__ clip, const float* __restrict__ conv_w,
                 const float* __restrict__ cls_w, const float* __restrict__ reg_w,
                 const float* __restrict__ w1, const float* __restrict__ w2,
                 u16* __restrict__ CH, u16* __restrict__ CL,
                 u16* __restrict__ WH, u16* __restrict__ WL,
                 u16* __restrict__ Z, float* __restrict__ HW,
                 float* __restrict__ w1T, float* __restrict__ w2T) {
    __shared__ float wsh[2304];
    int bid = blockIdx.x, t = threadIdx.x;
    if (bid < NB_CLIP) {
        int tid = bid * 256 + t;
        int c4  = (tid & 255) * 4;
        int pos = (tid >> 8) & 255;
        int b   = tid >> 16;
        float4 v = *(const float4*)(clip + ((size_t)(1 + pos) * 32 + b) * 1024 + c4);
        float xs[4] = {v.x, v.y, v.z, v.w};
        ushort4 hh, ll;
        u16* hp = (u16*)&hh; u16* lp = (u16*)&ll;
#pragma unroll
        for (int q = 0; q < 4; ++q) split16(xs[q], hp[q], lp[q]);
        size_t o = ((size_t)(b * 256 + pos)) * 1024 + c4;
        *(ushort4*)(CH + o) = hh;
        *(ushort4*)(CL + o) = ll;
    } else if (bid < NB_CLIP + NB_W) {
        int bid2 = bid - NB_CLIP;
        int o = bid2 >> 2, cblk = bid2 & 3;
        const float* src = conv_w + (size_t)o * K9 + cblk * 2304;
        for (int i = t; i < 2304; i += 256) wsh[i] = src[i];
        __syncthreads();
#pragma unroll
        for (int p = 0; p < 9; ++p) {
            float x = wsh[t * 9 + p];
            u16 h, l;
            split16(x, h, l);
            size_t o2 = (size_t)o * K9 + p * 1024 + cblk * 256 + t;
            WH[o2] = h; WL[o2] = l;
        }
    } else if (bid < NB_CLIP + NB_W + NB_Z) {
        Z[t] = 0; Z[256 + t] = 0;
    } else if (bid < NB_CLIP + NB_W + NB_Z + NB_HW) {
        // HW[c*45 + a] (round-0 layout: wave reads 45 consecutive floats per c)
        int tid2 = (bid - NB_CLIP - NB_W - NB_Z) * 256 + t;
        if (tid2 < 45 * 512) {
            int c = tid2 / 45, a = tid2 % 45;
            HW[tid2] = (a < 9) ? cls_w[a * 512 + c] : reg_w[(a - 9) * 512 + c];
        }
    } else if (bid < NB_CLIP + NB_W + NB_Z + NB_HW + NB_W1T) {
        int tid2 = (bid - NB_CLIP - NB_W - NB_Z - NB_HW) * 256 + t;
        int o = tid2 >> 10, c = tid2 & 1023;
        w1T[c * 256 + o] = w1[(size_t)o * 1024 + c];
    } else {
        int tid2 = (bid - NB_CLIP - NB_W - NB_Z - NB_HW - NB_W1T) * 256 + t;
        int o = tid2 >> 8, c = tid2 & 255;
        w2T[c * 256 + o] = w2[(size_t)o * 256 + c];
    }
}

// ---------------- MFMA conv GEMM (verified round-0 version: 128x128, 2 blocks/CU) ----------------
__global__ __launch_bounds__(256, 2)
void conv_mfma(const u16* __restrict__ CH, const u16* __restrict__ CL,
               const u16* __restrict__ WH, const u16* __restrict__ WL,
               const u16* __restrict__ ZS,
               float* __restrict__ XP0, float* __restrict__ XP1) {
    __shared__ __align__(16) u16 Ah[8192];
    __shared__ __align__(16) u16 Al[8192];
    __shared__ __align__(16) u16 Bh[8192];
    __shared__ __align__(16) u16 Bl[8192];

    const int t = threadIdx.x;
    const int gid = blockIdx.x;
    const int nb = gid >> 7;
    const int g  = gid & 127;
    const int mb = g >> 1;
    const int ks = g & 1;
    const int ksOff = ks * KHALF;
    float* __restrict__ XP = ks ? XP1 : XP0;

    const int wave = t >> 6, lane = t & 63;

    int qA[2], siA[2], sjA[2], bA[2];
    const u16* srcBh[2];
    const u16* srcBl[2];
#pragma unroll
    for (int j = 0; j < 2; ++j) {
        int r = wave * 32 + j * 16 + (lane >> 2);
        int s = lane & 3;
        int q = s ^ ((r >> 1) & 3);
        qA[j] = q;
        int m = mb * 128 + r;
        bA[j] = m >> 8;
        int ij = m & 255;
        siA[j] = ij >> 4; sjA[j] = ij & 15;
        int o = nb * 128 + r;
        srcBh[j] = WH + (size_t)o * K9 + q * 8;
        srcBl[j] = WL + (size_t)o * K9 + q * 8;
    }

    const int wm = wave >> 1, wn = wave & 1;
    const int l16 = lane & 15, quad = lane >> 4;
    int offA[4], offB[4];
#pragma unroll
    for (int q = 0; q < 4; ++q) {
        int ar = wm * 64 + q * 16 + l16;
        offA[q] = ar * 32 + ((quad ^ ((ar >> 1) & 3)) << 3);
        int br = wn * 64 + q * 16 + l16;
        offB[q] = br * 32 + ((quad ^ ((br >> 1) & 3)) << 3);
    }

    f32x4 acc[4][4];
#pragma unroll
    for (int r = 0; r < 4; ++r)
#pragma unroll
        for (int c = 0; c < 4; ++c) acc[r][c] = (f32x4){0.f, 0.f, 0.f, 0.f};

    auto issue = [&](int it, int buf) {
        const int kg = ksOff + it * 32;
        const int p = kg >> 10;
        const int cb = kg & 1023;
        const int di = p / 3, dj = p - di * 3;
        const int base = buf << 12;
#pragma unroll
        for (int j = 0; j < 2; ++j) {
            int ii = siA[j] + di - 1, jj = sjA[j] + dj - 1;
            bool ok = ((unsigned)ii < 16u) && ((unsigned)jj < 16u);
            size_t aoff = ok ? ((((size_t)bA[j] << 8) + (size_t)(ii * 16 + jj)) << 10) + cb + qA[j] * 8
                             : 0;
            const u16* gah = ok ? CH + aoff : ZS;
            const u16* gal = ok ? CL + aoff : ZS;
            int lb = base + wave * 1024 + j * 512;
            gl_lds16(gah,           &Ah[lb]);
            gl_lds16(gal,           &Al[lb]);
            gl_lds16(srcBh[j] + kg, &Bh[lb]);
            gl_lds16(srcBl[j] + kg, &Bl[lb]);
        }
    };

    issue(0, 0);
    for (int it = 0; it < 144; ++it) {
        const int cur = it & 1;
        __syncthreads();
        if (it + 1 < 144) issue(it + 1, cur ^ 1);

        const int fb = cur << 12;
        f16x8 fah[4], fal[4], fbh[4], fbl[4];
#pragma unroll
        for (int x = 0; x < 4; ++x) {
            fah[x] = *(const f16x8*)&Ah[fb + offA[x]];
            fal[x] = *(const f16x8*)&Al[fb + offA[x]];
            fbh[x] = *(const f16x8*)&Bh[fb + offB[x]];
            fbl[x] = *(const f16x8*)&Bl[fb + offB[x]];
        }
#pragma unroll
        for (int tm = 0; tm < 4; ++tm)
#pragma unroll
            for (int tn = 0; tn < 4; ++tn) {
                acc[tm][tn] = __builtin_amdgcn_mfma_f32_16x16x32_f16(fal[tm], fbh[tn], acc[tm][tn], 0, 0, 0);
                acc[tm][tn] = __builtin_amdgcn_mfma_f32_16x16x32_f16(fah[tm], fbl[tn], acc[tm][tn], 0, 0, 0);
                acc[tm][tn] = __builtin_amdgcn_mfma_f32_16x16x32_f16(fah[tm], fbh[tn], acc[tm][tn], 0, 0, 0);
            }
    }

#pragma unroll
    for (int tm = 0; tm < 4; ++tm) {
        int mbase = mb * 128 + wm * 64 + tm * 16 + quad * 4;
#pragma unroll
        for (int tn = 0; tn < 4; ++tn) {
            int o = nb * 128 + wn * 64 + tn * 16 + l16;
#pragma unroll
            for (int r = 0; r < 4; ++r)
                XP[(size_t)(mbase + r) * COUT + o] = acc[tm][tn][r];
        }
    }
}

// ---------------- heads (exact round-0 version) ----------------
__global__ __launch_bounds__(64)
void heads_kernel(const float* __restrict__ XP0, const float* __restrict__ XP1,
                  const float* __restrict__ conv_b, const float* __restrict__ HW,
                  const float* __restrict__ cls_b, const float* __restrict__ reg_b,
                  float* __restrict__ scores, float* __restrict__ regs) {
    __shared__ float xs[512];
    int mm = blockIdx.x;
    int t = threadIdx.x;
#pragma unroll
    for (int q = 0; q < 8; ++q) {
        int c = t + 64 * q;
        xs[c] = fmaxf(XP0[(size_t)mm * COUT + c] + XP1[(size_t)mm * COUT + c] + conv_b[c], 0.f);
    }
    __syncthreads();
    if (t < 45) {
        float acc = (t < 9) ? cls_b[t] : reg_b[t - 9];
        for (int c = 0; c < 512; ++c) acc = fmaf(xs[c], HW[c * 45 + t], acc);
        int b = mm >> 8, cell = mm & 255;
        if (t < 9) {
            scores[(size_t)b * 2304 + cell * 9 + t] = 1.f / (1.f + expf(-acc));
        } else {
            int ch = t - 9;
            regs[((size_t)b * 2304 + cell * 9 + (ch >> 2)) * 4 + (ch & 3)] = acc;
        }
    }
}

// ---------------- top-k + decode + NMS per image (unchanged) ----------------
__global__ __launch_bounds__(256)
void topk_nms(const float* __restrict__ scores, const float* __restrict__ regs,
              float* __restrict__ rois, float* __restrict__ valid) {
    __shared__ float sc[2304];
    __shared__ float wv[4];
    __shared__ int   wi[4];
    __shared__ int   sel[TOPK];
    __shared__ float bx[TOPK][4];
    __shared__ float iou[TOPK * TOPK];
    __shared__ float keepsh[TOPK];
    int b = blockIdx.x, t = threadIdx.x;
    for (int q = t; q < 2304; q += 256) sc[q] = scores[(size_t)b * 2304 + q];
    __syncthreads();

    for (int k = 0; k < TOPK; ++k) {
        float bv = -1e30f; int bi = 1 << 30;
#pragma unroll
        for (int q = 0; q < 9; ++q) {
            int idx = t * 9 + q;
            float v = sc[idx];
            if (v > bv || (v == bv && idx < bi)) { bv = v; bi = idx; }
        }
        for (int off = 32; off; off >>= 1) {
            float ov = __shfl_down(bv, off);
            int   oi = __shfl_down(bi, off);
            if (ov > bv || (ov == bv && oi < bi)) { bv = ov; bi = oi; }
        }
        int lane = t & 63, w = t >> 6;
        if (lane == 0) { wv[w] = bv; wi[w] = bi; }
        __syncthreads();
        if (t == 0) {
            float fv = wv[0]; int fi = wi[0];
            for (int q = 1; q < 4; ++q)
                if (wv[q] > fv || (wv[q] == fv && wi[q] < fi)) { fv = wv[q]; fi = wi[q]; }
            sel[k] = fi;
            sc[fi] = -1e38f;
        }
        __syncthreads();
    }

    if (t < TOPK) {
        int n = sel[t];
        int cell = n / 9, a = n % 9;
        int ci = cell >> 4, cj = cell & 15;
        int siid = a / 3, riid = a % 3;
        const double scl[3] = {8.0, 16.0, 32.0};
        const double rat[3] = {0.5, 1.0, 2.0};
        double s = scl[siid], r = rat[riid];
        double wD = s * sqrt(r), hD = s / sqrt(r);
        double xc = (cj + 0.5) * 16.0, yc = (ci + 0.5) * 16.0;
        float ax1 = (float)(xc - wD / 2), ay1 = (float)(yc - hD / 2);
        float ax2 = (float)(xc + wD / 2), ay2 = (float)(yc + hD / 2);
        float aw = ax2 - ax1, ah = ay2 - ay1;
        float ctrx = ax1 + 0.5f * aw, ctry = ay1 + 0.5f * ah;
        const float* rg = regs + ((size_t)b * 2304 + n) * 4;
        float cx = rg[0] * aw + ctrx;
        float cy = rg[1] * ah + ctry;
        float pw = expf(rg[2]) * aw;
        float ph = expf(rg[3]) * ah;
        float x1 = cx - 0.5f * pw, y1 = cy - 0.5f * ph;
        float x2 = cx + 0.5f * pw, y2 = cy + 0.5f * ph;
        x1 = fminf(fmaxf(x1, 0.f), 256.f);
        y1 = fminf(fmaxf(y1, 0.f), 256.f);
        x2 = fminf(fmaxf(x2, 0.f), 256.f);
        y2 = fminf(fmaxf(y2, 0.f), 256.f);
        if (x2 - x1 < 1.f) x2 = x1 + 1.f;
        if (y2 - y1 < 1.f) y2 = y1 + 1.f;
        bx[t][0] = x1; bx[t][1] = y1; bx[t][2] = x2; bx[t][3] = y2;
    }
    __syncthreads();
    if (t < TOPK * TOPK) {
        int ii = t / TOPK, jj = t % TOPK;
        float xi1 = bx[ii][0], yi1 = bx[ii][1], xi2 = bx[ii][2], yi2 = bx[ii][3];
        float xj1 = bx[jj][0], yj1 = bx[jj][1], xj2 = bx[jj][2], yj2 = bx[jj][3];
        float ai = (xi2 - xi1) * (yi2 - yi1), aj = (xj2 - xj1) * (yj2 - yj1);
        float iw = fmaxf(fminf(xi2, xj2) - fmaxf(xi1, xj1), 0.f);
        float ih = fmaxf(fminf(yi2, yj2) - fmaxf(yi1, yj1), 0.f);
        float inter = iw * ih;
        iou[t] = inter / (ai + aj - inter);
    }
    __syncthreads();
    if (t == 0) {
        bool keep[TOPK];
        for (int q = 0; q < TOPK; ++q) keep[q] = true;
        for (int iK = 0; iK < TOPK; ++iK) {
            if (!keep[iK]) continue;
            for (int jK = iK + 1; jK < TOPK; ++jK)
                if (keep[jK] && iou[iK * TOPK + jK] > 0.85f) keep[jK] = false;
        }
        for (int q = 0; q < TOPK; ++q) keepsh[q] = keep[q] ? 1.f : 0.f;
    }
    __syncthreads();
    if (t < TOPK) {
        int rr = b * TOPK + t;
        rois[rr * 4 + 0] = bx[t][0]; rois[rr * 4 + 1] = bx[t][1];
        rois[rr * 4 + 2] = bx[t][2]; rois[rr * 4 + 3] = bx[t][3];
        valid[rr] = keepsh[t];
    }
}

// ---------------- roi-align, image-sliced (unchanged) ----------------
__global__ __launch_bounds__(256)
void align_img(const float* __restrict__ clip, const float* __restrict__ rois,
               float* __restrict__ pooled) {
    __shared__ float slice[16384];   // 64 KB: [pos 0..255][ch 0..63]
    int bid = blockIdx.x;            // 0..511
    int b = bid >> 4, cg = bid & 15;
    int t = threadIdx.x;
    for (int idx = t; idx < 16384; idx += 256) {
        int p = idx >> 6, c = idx & 63;
        slice[idx] = clip[(size_t)(1 + p) * 32768 + (size_t)b * 1024 + cg * 64 + c];
    }
    __syncthreads();
    int wv = t >> 6;
    int ch = t & 63;
    for (int rp = 0; rp < 8; ++rp) {
        int rl = rp * 4 + wv;
        if (rl >= TOPK) continue;
        int r = b * TOPK + rl;
        float rx1 = rois[r * 4 + 0] * 0.0625f, ry1 = rois[r * 4 + 1] * 0.0625f;
        float rw = fmaxf(rois[r * 4 + 2] * 0.0625f - rx1, 1.f);
        float rh = fmaxf(rois[r * 4 + 3] * 0.0625f - ry1, 1.f);
        float sx = rw / (float)POOLN, sy = rh / (float)POOLN;
        float acc = 0.f;
        for (int py = 0; py < POOLN; ++py) {
            float Y = ry1 + ((float)py + 0.5f) * sy;
            for (int px = 0; px < POOLN; ++px) {
                float Xx = rx1 + ((float)px + 0.5f) * sx;
                bool ok = (Y > -1.f) && (Y < 16.f) && (Xx > -1.f) && (Xx < 16.f);
                if (!ok) continue;
                float Xc = fminf(fmaxf(Xx, 0.f), 15.f);
                float Yc = fminf(fmaxf(Y, 0.f), 15.f);
                int x0 = (int)floorf(Xc), y0 = (int)floorf(Yc);
                int x1i = min(x0 + 1, 15), y1i = min(y0 + 1, 15);
                float lx = Xc - (float)x0, ly = Yc - (float)y0;
                float hx = 1.f - lx, hy = 1.f - ly;
                float w00 = hy * hx, w01 = hy * lx, w10 = ly * hx, w11 = ly * lx;
                float f00 = slice[(y0 * 16 + x0) * 64 + ch];
                float f01 = slice[(y0 * 16 + x1i) * 64 + ch];
                float f10 = slice[(y1i * 16 + x0) * 64 + ch];
                float f11 = slice[(y1i * 16 + x1i) * 64 + ch];
                acc += w00 * f00 + w01 * f01 + w10 * f10 + w11 * f11;
            }
        }
        pooled[(size_t)r * 1024 + cg * 64 + ch] = acc / 49.f;
    }
}

// ---------------- roi labels (unchanged) ----------------
__global__ __launch_bounds__(256)
void labels_k(const float* __restrict__ gt, const float* __restrict__ rois,
              float* __restrict__ labels) {
    __shared__ float red[4];
    int r = blockIdx.x, t = threadIdx.x;
    int b = r / TOPK;
    int x1 = min(max((int)rois[r * 4 + 0], 0), 256);
    int y1 = min(max((int)rois[r * 4 + 1], 0), 256);
    int x2 = min(max((int)rois[r * 4 + 2], 0), 256);
    int y2 = min(max((int)rois[r * 4 + 3], 0), 256);
    int cnt = (x2 - x1) * (y2 - y1);
    float s = 0.f;
    if (cnt > 0) {
        const float* g = gt + (size_t)b * (IMG * IMG);
        for (int yy = y1; yy < y2; ++yy) {
            const float* row = g + yy * IMG;
            for (int xx = x1 + t; xx < x2; xx += 256) s += row[xx];
        }
    }
    for (int off = 32; off; off >>= 1) s += __shfl_down(s, off);
    if ((t & 63) == 0) red[t >> 6] = s;
    __syncthreads();
    if (t == 0) {
        float tot = red[0] + red[1] + red[2] + red[3];
        labels[r] = (cnt > 0 && 2.f * tot > (float)cnt) ? 1.f : 0.f;
    }
}

// ---------------- fused fc1(relu) -> fc2 -> normalize, 4 rois/block ----------------
__global__ __launch_bounds__(256)
void fc_norm(const float* __restrict__ pooled, const float* __restrict__ w1T,
             const float* __restrict__ b1, const float* __restrict__ w2T,
             const float* __restrict__ b2, float* __restrict__ nf) {
    __shared__ float rows[4][1024];
    __shared__ float hsh[4][256];
    __shared__ float red[4];
    int r0 = blockIdx.x * 4, t = threadIdx.x;
    for (int q = 0; q < 4; ++q)
        for (int c = t; c < 1024; c += 256)
            rows[q][c] = pooled[(size_t)(r0 + q) * 1024 + c];
    __syncthreads();
    {
        float bv = b1[t];
        float acc[4] = {bv, bv, bv, bv};
        for (int c = 0; c < 1024; ++c) {
            float wv = w1T[c * 256 + t];
#pragma unroll
            for (int q = 0; q < 4; ++q) acc[q] = fmaf(rows[q][c], wv, acc[q]);
        }
#pragma unroll
        for (int q = 0; q < 4; ++q) hsh[q][t] = fmaxf(acc[q], 0.f);
    }
    __syncthreads();
    float pr[4];
    {
        float bv = b2[t];
        float acc[4] = {bv, bv, bv, bv};
        for (int c = 0; c < 256; ++c) {
            float wv = w2T[c * 256 + t];
#pragma unroll
            for (int q = 0; q < 4; ++q) acc[q] = fmaf(hsh[q][c], wv, acc[q]);
        }
#pragma unroll
        for (int q = 0; q < 4; ++q) pr[q] = acc[q];
    }
    for (int q = 0; q < 4; ++q) {
        float v = pr[q];
        float ss = v * v;
        for (int off = 32; off; off >>= 1) ss += __shfl_down(ss, off);
        if ((t & 63) == 0) red[t >> 6] = ss;
        __syncthreads();
        float tot = red[0] + red[1] + red[2] + red[3];
        float denom = fmaxf(sqrtf(tot), 1e-12f);
        nf[(size_t)(r0 + q) * 256 + t] = v / denom;
        __syncthreads();
    }
}

// ---------------- supcon, tiled outer-product version ----------------
// grid = 30 i-tiles(32) x 15 j-tiles(64) = 450 blocks, 256 thr (4 waves).
// Wave w owns 8 i-rows; lane owns one j. j-tile staged row-major [64][256] f32 with
// 16B-slot XOR swizzle (byte ^= (j&7)<<4) so per-lane b128 row reads are conflict-free
// (min 8-cycle wave64 b128). i-rows staged plain (broadcast reads). Per (i,j): e/pos/np
// masks replicate supcon_half exactly; PS[i][jt][3] always written (ws poisoned).
__global__ __launch_bounds__(256)
void supcon_tile(const float* __restrict__ nf, const float* __restrict__ labels,
                 const float* __restrict__ valid, float* __restrict__ PS) {
    __shared__ __align__(16) float nfT[64 * 256];   // swizzled [j][c]
    __shared__ __align__(16) float myl[32 * 256];   // [i][c]
    __shared__ float labj[64], valj[64];
    int bid = blockIdx.x;
    int it = bid / SJT, jt = bid - it * SJT;
    int i0 = it * 32, j0 = jt * 64;
    int t = threadIdx.x;

    for (int idx = t; idx < 64 * 256; idx += 256) {
        int j = idx >> 8, c = idx & 255;
        float v = nf[(size_t)(j0 + j) * 256 + c];
        int byte_off = ((j << 10) + (c << 2)) ^ ((j & 7) << 4);
        *(float*)((char*)nfT + byte_off) = v;
    }
    for (int idx = t; idx < 32 * 256; idx += 256)
        myl[idx] = nf[(size_t)i0 * 256 + idx];
    if (t < 64) { labj[t] = labels[j0 + t]; valj[t] = valid[j0 + t]; }
    __syncthreads();

    int w = t >> 6, lane = t & 63;
    const char* jrow = (const char*)nfT + (lane << 10);
    const int sw = (lane & 7) << 4;
    const float* my0 = &myl[(w * 8) * 256];

    float d[8];
#pragma unroll
    for (int q = 0; q < 8; ++q) d[q] = 0.f;
    for (int c = 0; c < 256; c += 4) {
        float4 b4 = *(const float4*)(jrow + ((c << 2) ^ sw));
#pragma unroll
        for (int q = 0; q < 8; ++q) {
            float4 a4 = *(const float4*)(my0 + q * 256 + c);
            d[q] = fmaf(a4.x, b4.x, d[q]);
            d[q] = fmaf(a4.y, b4.y, d[q]);
            d[q] = fmaf(a4.z, b4.z, d[q]);
            d[q] = fmaf(a4.w, b4.w, d[q]);
        }
    }

    int jg = j0 + lane;
    float vj = valj[lane], lj = labj[lane];
#pragma unroll
    for (int q = 0; q < 8; ++q) {
        int ig = i0 + w * 8 + q;
        float vi = valid[ig];
        float li = labels[ig];
        bool vmask = (vi > 0.5f) && (vj > 0.5f) && (jg != ig);
        float e  = vmask ? expf(d[q] / 0.07f) : 0.f;
        bool pos = vmask && (lj == li);
        float ep  = pos ? e : 0.f;
        float npv = pos ? 1.f : 0.f;
        float sa = e, sp = ep, sn = npv;
#pragma unroll
        for (int off = 32; off; off >>= 1) {
            sa += __shfl_xor(sa, off);
            sp += __shfl_xor(sp, off);
            sn += __shfl_xor(sn, off);
        }
        if (lane == 0) {
            size_t o = ((size_t)ig * SJT + jt) * 3;
            PS[o + 0] = sa;
            PS[o + 1] = sp;
            PS[o + 2] = sn;
        }
    }
}

// ---------------- final: combine SJT tiles, per-row loss, mean ----------------
__global__ __launch_bounds__(256)
void final_reduce2(const float* __restrict__ PS, const float* __restrict__ valid,
                   float* __restrict__ out) {
    __shared__ float rl[4], ra[4];
    int t = threadIdx.x;
    float sl = 0.f, sc = 0.f;
    for (int i = t; i < NROI; i += 256) {
        float sa = 0.f, sp = 0.f, np = 0.f;
        for (int jt = 0; jt < SJT; ++jt) {
            size_t o = ((size_t)i * SJT + jt) * 3;
            sa += PS[o + 0];
            sp += PS[o + 1];
            np += PS[o + 2];
        }
        bool active = (valid[i] > 0.5f) && (np > 0.5f);
        float ratio = sp / (sa + 1e-12f);
        float l = -logf(ratio + 1e-12f);
        sl += active ? l : 0.f;
        sc += active ? 1.f : 0.f;
    }
    for (int off = 32; off; off >>= 1) { sl += __shfl_down(sl, off); sc += __shfl_down(sc, off); }
    if ((t & 63) == 0) { rl[t >> 6] = sl; ra[t >> 6] = sc; }
    __syncthreads();
    if (t == 0) {
        float L = rl[0] + rl[1] + rl[2] + rl[3];
        float A = ra[0] + ra[1] + ra[2] + ra[3];
        out[0] = (A > 0.f) ? (L / fmaxf(A, 1.f)) : 0.f;
    }
}

// ---------------- launch ----------------
extern "C" void kernel_launch(void* const* d_in, const int* in_sizes, int n_in,
                              void* d_out, int out_size, void* d_ws, size_t ws_size,
                              hipStream_t stream) {
    const float* clip   = (const float*)d_in[0];
    const float* gt     = (const float*)d_in[1];
    const float* conv_w = (const float*)d_in[2];
    const float* conv_b = (const float*)d_in[3];
    const float* cls_w  = (const float*)d_in[4];
    const float* cls_b  = (const float*)d_in[5];
    const float* reg_w  = (const float*)d_in[6];
    const float* reg_b  = (const float*)d_in[7];
    const float* w1     = (const float*)d_in[8];
    const float* b1     = (const float*)d_in[9];
    const float* w2     = (const float*)d_in[10];
    const float* b2     = (const float*)d_in[11];

    if (ws_size < WS_FLOATS * sizeof(float)) return;  // visible failure if ws too small

    float* ws  = (float*)d_ws;
    float* XP0 = ws + O_XP0;
    float* XP1 = ws + O_XP1;
    u16*   CH  = (u16*)(ws + O_CH);
    u16*   CL  = (u16*)(ws + O_CL);
    u16*   WHp = (u16*)(ws + O_WH);
    u16*   WLp = (u16*)(ws + O_WL);
    u16*   ZS  = (u16*)(ws + O_Z);
    float* HW  = ws + O_HW;
    float* SC  = ws + O_SC;
    float* RG  = ws + O_RG;
    float* ROI = ws + O_ROI;
    float* VAL = ws + O_VAL;
    float* LAB = ws + O_LAB;
    float* W1T = ws + O_W1T;
    float* W2T = ws + O_W2T;
    float* PO  = ws + O_PO;
    float* NF  = ws + O_NF;
    float* PS  = ws + O_PS;

    convert_all<<<NB_CLIP + NB_W + NB_Z + NB_HW + NB_W1T + NB_W2T, 256, 0, stream>>>(
        clip, conv_w, cls_w, reg_w, w1, w2, CH, CL, WHp, WLp, ZS, HW, W1T, W2T);
    conv_mfma<<<512, 256, 0, stream>>>(CH, CL, WHp, WLp, ZS, XP0, XP1);
    heads_kernel<<<NPOS, 64, 0, stream>>>(XP0, XP1, conv_b, HW, cls_b, reg_b, SC, RG);
    topk_nms<<<BATCH, 256, 0, stream>>>(SC, RG, ROI, VAL);
    align_img<<<512, 256, 0, stream>>>(clip, ROI, PO);
    labels_k<<<NROI, 256, 0, stream>>>(gt, ROI, LAB);
    fc_norm<<<NROI / 4, 256, 0, stream>>>(PO, W1T, b1, W2T, b2, NF);
    supcon_tile<<<30 * SJT, 256, 0, stream>>>(NF, LAB, VAL, PS);
    final_reduce2<<<1, 256, 0, stream>>>(PS, VAL, (float*)d_out);
}

// Round 5
// 602.911 us; speedup vs baseline: 1.2328x; 1.0772x over previous
//
#include <hip/hip_runtime.h>
#include <hip/hip_bf16.h>
#include <math.h>

typedef unsigned short u16;
typedef unsigned int u32;
typedef _Float16 f16;
typedef _Float16 f16x8 __attribute__((ext_vector_type(8)));
typedef float f32x4 __attribute__((ext_vector_type(4)));

// ---------------- constants ----------------
#define BATCH 32
#define CIN   1024
#define COUT  512
#define NPOS  8192
#define K9    9216
#define KHALF 4608
#define TOPK  30
#define NROI  960
#define POOLN 7
#define IMG   256
#define SJT   15      // supcon j-tiles of 64 (960/64)
#define HB_POS 32     // heads positions per block

// ---------------- ws layout (float units) ----------------
#define O_XP0  0ull
#define O_XP1  4194304ull
#define O_CH   8388608ull      // u16[8388608]
#define O_CL   12582912ull
#define O_WH   16777216ull     // u16[4718592]
#define O_WL   19136512ull
#define O_Z    21495808ull     // 512 u16 zeros
#define O_HW   21496064ull     // float[23040] head weights TRANSPOSED [a][c] (heads stages to LDS)
#define O_SC   21519104ull
#define O_RG   21592832ull
#define O_ROI  21887744ull
#define O_VAL  21891584ull
#define O_LAB  21892544ull
#define O_W1T  21893504ull     // float[262144] w1 transposed [c][o]
#define O_W2T  22155648ull     // float[65536]  w2 transposed [c][o]
#define WS_FLOATS 22221184ull
// overlays on XP0/XP1 region (used only after heads consumed XP0/XP1):
#define O_PO   0ull
#define O_NF   1474560ull
#define O_PS   1720320ull      // float[960][SJT][3] supcon partials (43200 floats)

// async global->LDS, 16 bytes/lane, LDS dest = wave-uniform base + lane*16
__device__ __forceinline__ void gl_lds16(const void* g, void* l) {
    __builtin_amdgcn_global_load_lds(
        (const __attribute__((address_space(1))) u32*)g,
        (__attribute__((address_space(3))) u32*)l,
        16, 0, 0);
}

// ---------------- fp16 hi/lo split ----------------
__device__ inline void split16(float x, u16& h, u16& l) {
    f16 hv = (f16)x;
    f16 lv = (f16)(x - (float)hv);
    h = *(u16*)&hv;
    l = *(u16*)&lv;
}

// ---------------- fused prep ----------------
#define NB_CLIP 8192
#define NB_W    2048
#define NB_Z    1
#define NB_HW   90
#define NB_W1T  1024
#define NB_W2T  256
__global__ __launch_bounds__(256)
void convert_all(const float* __restrict__ clip, const float* __restrict__ conv_w,
                 const float* __restrict__ cls_w, const float* __restrict__ reg_w,
                 const float* __restrict__ w1, const float* __restrict__ w2,
                 u16* __restrict__ CH, u16* __restrict__ CL,
                 u16* __restrict__ WH, u16* __restrict__ WL,
                 u16* __restrict__ Z, float* __restrict__ HW,
                 float* __restrict__ w1T, float* __restrict__ w2T) {
    __shared__ float wsh[2304];
    int bid = blockIdx.x, t = threadIdx.x;
    if (bid < NB_CLIP) {
        int tid = bid * 256 + t;
        int c4  = (tid & 255) * 4;
        int pos = (tid >> 8) & 255;
        int b   = tid >> 16;
        float4 v = *(const float4*)(clip + ((size_t)(1 + pos) * 32 + b) * 1024 + c4);
        float xs[4] = {v.x, v.y, v.z, v.w};
        ushort4 hh, ll;
        u16* hp = (u16*)&hh; u16* lp = (u16*)&ll;
#pragma unroll
        for (int q = 0; q < 4; ++q) split16(xs[q], hp[q], lp[q]);
        size_t o = ((size_t)(b * 256 + pos)) * 1024 + c4;
        *(ushort4*)(CH + o) = hh;
        *(ushort4*)(CL + o) = ll;
    } else if (bid < NB_CLIP + NB_W) {
        int bid2 = bid - NB_CLIP;
        int o = bid2 >> 2, cblk = bid2 & 3;
        const float* src = conv_w + (size_t)o * K9 + cblk * 2304;
        for (int i = t; i < 2304; i += 256) wsh[i] = src[i];
        __syncthreads();
#pragma unroll
        for (int p = 0; p < 9; ++p) {
            float x = wsh[t * 9 + p];
            u16 h, l;
            split16(x, h, l);
            size_t o2 = (size_t)o * K9 + p * 1024 + cblk * 256 + t;
            WH[o2] = h; WL[o2] = l;
        }
    } else if (bid < NB_CLIP + NB_W + NB_Z) {
        Z[t] = 0; Z[256 + t] = 0;
    } else if (bid < NB_CLIP + NB_W + NB_Z + NB_HW) {
        // head weights, transposed [a][c] (contiguous copy; heads stages to LDS coalesced)
        int tid2 = (bid - NB_CLIP - NB_W - NB_Z) * 256 + t;
        if (tid2 < 45 * 512) {
            int a = tid2 >> 9, c = tid2 & 511;
            HW[tid2] = (a < 9) ? cls_w[a * 512 + c] : reg_w[(a - 9) * 512 + c];
        }
    } else if (bid < NB_CLIP + NB_W + NB_Z + NB_HW + NB_W1T) {
        int tid2 = (bid - NB_CLIP - NB_W - NB_Z - NB_HW) * 256 + t;
        int o = tid2 >> 10, c = tid2 & 1023;
        w1T[c * 256 + o] = w1[(size_t)o * 1024 + c];
    } else {
        int tid2 = (bid - NB_CLIP - NB_W - NB_Z - NB_HW - NB_W1T) * 256 + t;
        int o = tid2 >> 8, c = tid2 & 255;
        w2T[c * 256 + o] = w2[(size_t)o * 256 + c];
    }
}

// ---------------- MFMA conv GEMM (verified round-0 version: 128x128, 2 blocks/CU) ----------------
__global__ __launch_bounds__(256, 2)
void conv_mfma(const u16* __restrict__ CH, const u16* __restrict__ CL,
               const u16* __restrict__ WH, const u16* __restrict__ WL,
               const u16* __restrict__ ZS,
               float* __restrict__ XP0, float* __restrict__ XP1) {
    __shared__ __align__(16) u16 Ah[8192];
    __shared__ __align__(16) u16 Al[8192];
    __shared__ __align__(16) u16 Bh[8192];
    __shared__ __align__(16) u16 Bl[8192];

    const int t = threadIdx.x;
    const int gid = blockIdx.x;
    const int nb = gid >> 7;
    const int g  = gid & 127;
    const int mb = g >> 1;
    const int ks = g & 1;
    const int ksOff = ks * KHALF;
    float* __restrict__ XP = ks ? XP1 : XP0;

    const int wave = t >> 6, lane = t & 63;

    int qA[2], siA[2], sjA[2], bA[2];
    const u16* srcBh[2];
    const u16* srcBl[2];
#pragma unroll
    for (int j = 0; j < 2; ++j) {
        int r = wave * 32 + j * 16 + (lane >> 2);
        int s = lane & 3;
        int q = s ^ ((r >> 1) & 3);
        qA[j] = q;
        int m = mb * 128 + r;
        bA[j] = m >> 8;
        int ij = m & 255;
        siA[j] = ij >> 4; sjA[j] = ij & 15;
        int o = nb * 128 + r;
        srcBh[j] = WH + (size_t)o * K9 + q * 8;
        srcBl[j] = WL + (size_t)o * K9 + q * 8;
    }

    const int wm = wave >> 1, wn = wave & 1;
    const int l16 = lane & 15, quad = lane >> 4;
    int offA[4], offB[4];
#pragma unroll
    for (int q = 0; q < 4; ++q) {
        int ar = wm * 64 + q * 16 + l16;
        offA[q] = ar * 32 + ((quad ^ ((ar >> 1) & 3)) << 3);
        int br = wn * 64 + q * 16 + l16;
        offB[q] = br * 32 + ((quad ^ ((br >> 1) & 3)) << 3);
    }

    f32x4 acc[4][4];
#pragma unroll
    for (int r = 0; r < 4; ++r)
#pragma unroll
        for (int c = 0; c < 4; ++c) acc[r][c] = (f32x4){0.f, 0.f, 0.f, 0.f};

    auto issue = [&](int it, int buf) {
        const int kg = ksOff + it * 32;
        const int p = kg >> 10;
        const int cb = kg & 1023;
        const int di = p / 3, dj = p - di * 3;
        const int base = buf << 12;
#pragma unroll
        for (int j = 0; j < 2; ++j) {
            int ii = siA[j] + di - 1, jj = sjA[j] + dj - 1;
            bool ok = ((unsigned)ii < 16u) && ((unsigned)jj < 16u);
            size_t aoff = ok ? ((((size_t)bA[j] << 8) + (size_t)(ii * 16 + jj)) << 10) + cb + qA[j] * 8
                             : 0;
            const u16* gah = ok ? CH + aoff : ZS;
            const u16* gal = ok ? CL + aoff : ZS;
            int lb = base + wave * 1024 + j * 512;
            gl_lds16(gah,           &Ah[lb]);
            gl_lds16(gal,           &Al[lb]);
            gl_lds16(srcBh[j] + kg, &Bh[lb]);
            gl_lds16(srcBl[j] + kg, &Bl[lb]);
        }
    };

    issue(0, 0);
    for (int it = 0; it < 144; ++it) {
        const int cur = it & 1;
        __syncthreads();
        if (it + 1 < 144) issue(it + 1, cur ^ 1);

        const int fb = cur << 12;
        f16x8 fah[4], fal[4], fbh[4], fbl[4];
#pragma unroll
        for (int x = 0; x < 4; ++x) {
            fah[x] = *(const f16x8*)&Ah[fb + offA[x]];
            fal[x] = *(const f16x8*)&Al[fb + offA[x]];
            fbh[x] = *(const f16x8*)&Bh[fb + offB[x]];
            fbl[x] = *(const f16x8*)&Bl[fb + offB[x]];
        }
#pragma unroll
        for (int tm = 0; tm < 4; ++tm)
#pragma unroll
            for (int tn = 0; tn < 4; ++tn) {
                acc[tm][tn] = __builtin_amdgcn_mfma_f32_16x16x32_f16(fal[tm], fbh[tn], acc[tm][tn], 0, 0, 0);
                acc[tm][tn] = __builtin_amdgcn_mfma_f32_16x16x32_f16(fah[tm], fbl[tn], acc[tm][tn], 0, 0, 0);
                acc[tm][tn] = __builtin_amdgcn_mfma_f32_16x16x32_f16(fah[tm], fbh[tn], acc[tm][tn], 0, 0, 0);
            }
    }

#pragma unroll
    for (int tm = 0; tm < 4; ++tm) {
        int mbase = mb * 128 + wm * 64 + tm * 16 + quad * 4;
#pragma unroll
        for (int tn = 0; tn < 4; ++tn) {
            int o = nb * 128 + wn * 64 + tn * 16 + l16;
#pragma unroll
            for (int r = 0; r < 4; ++r)
                XP[(size_t)(mbase + r) * COUT + o] = acc[tm][tn][r];
        }
    }
}

// ---------------- heads v2: supcon-style tiled dot (LDS-staged X and W) ----------------
// grid 256 blocks x 256 thr. Block = 32 positions. Lane = (pos, c-half); wave owns 12 of
// 45 outputs. X rows XOR-swizzled for b128 at wave64 floor; W rows uniform-broadcast.
__global__ __launch_bounds__(256)
void heads_kernel(const float* __restrict__ XP0, const float* __restrict__ XP1,
                  const float* __restrict__ conv_b, const float* __restrict__ HWT,
                  const float* __restrict__ cls_b, const float* __restrict__ reg_b,
                  float* __restrict__ scores, float* __restrict__ regs) {
    __shared__ __align__(16) float Xs[HB_POS * 512];   // swizzled [pos][c], 64 KB
    __shared__ __align__(16) float Ws[45 * 512];       // [a][c], 90 KB
    int t = threadIdx.x;
    int mm0 = blockIdx.x * HB_POS;

    // stage X = relu(XP0+XP1+conv_b), float4 coalesced, swizzle byte ^= (pos&7)<<4
    for (int idx = t; idx < HB_POS * 128; idx += 256) {
        int p = idx >> 7, cq = idx & 127;
        int mm = mm0 + p;
        float4 a = *(const float4*)(XP0 + (size_t)mm * COUT + cq * 4);
        float4 b = *(const float4*)(XP1 + (size_t)mm * COUT + cq * 4);
        float4 cv = *(const float4*)(conv_b + cq * 4);
        float4 r;
        r.x = fmaxf(a.x + b.x + cv.x, 0.f);
        r.y = fmaxf(a.y + b.y + cv.y, 0.f);
        r.z = fmaxf(a.z + b.z + cv.z, 0.f);
        r.w = fmaxf(a.w + b.w + cv.w, 0.f);
        int byte_off = ((p << 11) + (cq << 4)) ^ ((p & 7) << 4);
        *(float4*)((char*)Xs + byte_off) = r;
    }
    // stage W coalesced (45*512/4 = 5760 float4)
    for (int idx = t; idx < 5760; idx += 256)
        ((float4*)Ws)[idx] = ((const float4*)HWT)[idx];
    __syncthreads();

    int w = t >> 6, lane = t & 63;
    int p = lane & 31, half = lane >> 5;
    const char* xrow = (const char*)Xs + (p << 11) + (half << 10);
    const int swz = (p & 7) << 4;
    int a0 = w * 12;
    const float* wrow[12];
#pragma unroll
    for (int k = 0; k < 12; ++k) {
        int ak = a0 + k; if (ak > 44) ak = 44;   // clamp (discarded on write)
        wrow[k] = Ws + ak * 512 + half * 256;
    }

    float acc[12];
#pragma unroll
    for (int k = 0; k < 12; ++k) acc[k] = 0.f;
    for (int cq = 0; cq < 64; ++cq) {
        float4 x4 = *(const float4*)(xrow + ((cq << 4) ^ swz));
#pragma unroll
        for (int k = 0; k < 12; ++k) {
            float4 w4 = *(const float4*)(wrow[k] + cq * 4);
            acc[k] = fmaf(x4.x, w4.x, acc[k]);
            acc[k] = fmaf(x4.y, w4.y, acc[k]);
            acc[k] = fmaf(x4.z, w4.z, acc[k]);
            acc[k] = fmaf(x4.w, w4.w, acc[k]);
        }
    }
    // fold the two c-halves
#pragma unroll
    for (int k = 0; k < 12; ++k) acc[k] += __shfl_xor(acc[k], 32);

    if (half == 0) {
        int mm = mm0 + p;
        int b = mm >> 8, cell = mm & 255;
#pragma unroll
        for (int k = 0; k < 12; ++k) {
            int a = a0 + k;
            if (a < 45) {
                if (a < 9) {
                    float v = acc[k] + cls_b[a];
                    scores[(size_t)b * 2304 + cell * 9 + a] = 1.f / (1.f + expf(-v));
                } else {
                    int ch = a - 9;
                    float v = acc[k] + reg_b[ch];
                    regs[((size_t)b * 2304 + cell * 9 + (ch >> 2)) * 4 + (ch & 3)] = v;
                }
            }
        }
    }
}

// ---------------- top-k + decode + NMS per image (parallel NMS suppression) ----------------
__global__ __launch_bounds__(256)
void topk_nms(const float* __restrict__ scores, const float* __restrict__ regs,
              float* __restrict__ rois, float* __restrict__ valid) {
    __shared__ float sc[2304];
    __shared__ float wv[4];
    __shared__ int   wi[4];
    __shared__ int   sel[TOPK];
    __shared__ float bx[TOPK][4];
    __shared__ float iou[TOPK * TOPK];
    __shared__ float keepsh[TOPK];
    int b = blockIdx.x, t = threadIdx.x;
    for (int q = t; q < 2304; q += 256) sc[q] = scores[(size_t)b * 2304 + q];
    __syncthreads();

    for (int k = 0; k < TOPK; ++k) {
        float bv = -1e30f; int bi = 1 << 30;
#pragma unroll
        for (int q = 0; q < 9; ++q) {
            int idx = t * 9 + q;
            float v = sc[idx];
            if (v > bv || (v == bv && idx < bi)) { bv = v; bi = idx; }
        }
        for (int off = 32; off; off >>= 1) {
            float ov = __shfl_down(bv, off);
            int   oi = __shfl_down(bi, off);
            if (ov > bv || (ov == bv && oi < bi)) { bv = ov; bi = oi; }
        }
        int lane = t & 63, w = t >> 6;
        if (lane == 0) { wv[w] = bv; wi[w] = bi; }
        __syncthreads();
        if (t == 0) {
            float fv = wv[0]; int fi = wi[0];
            for (int q = 1; q < 4; ++q)
                if (wv[q] > fv || (wv[q] == fv && wi[q] < fi)) { fv = wv[q]; fi = wi[q]; }
            sel[k] = fi;
            sc[fi] = -1e38f;
        }
        __syncthreads();
    }

    if (t < TOPK) {
        int n = sel[t];
        int cell = n / 9, a = n % 9;
        int ci = cell >> 4, cj = cell & 15;
        int siid = a / 3, riid = a % 3;
        const double scl[3] = {8.0, 16.0, 32.0};
        const double rat[3] = {0.5, 1.0, 2.0};
        double s = scl[siid], r = rat[riid];
        double wD = s * sqrt(r), hD = s / sqrt(r);
        double xc = (cj + 0.5) * 16.0, yc = (ci + 0.5) * 16.0;
        float ax1 = (float)(xc - wD / 2), ay1 = (float)(yc - hD / 2);
        float ax2 = (float)(xc + wD / 2), ay2 = (float)(yc + hD / 2);
        float aw = ax2 - ax1, ah = ay2 - ay1;
        float ctrx = ax1 + 0.5f * aw, ctry = ay1 + 0.5f * ah;
        const float* rg = regs + ((size_t)b * 2304 + n) * 4;
        float cx = rg[0] * aw + ctrx;
        float cy = rg[1] * ah + ctry;
        float pw = expf(rg[2]) * aw;
        float ph = expf(rg[3]) * ah;
        float x1 = cx - 0.5f * pw, y1 = cy - 0.5f * ph;
        float x2 = cx + 0.5f * pw, y2 = cy + 0.5f * ph;
        x1 = fminf(fmaxf(x1, 0.f), 256.f);
        y1 = fminf(fmaxf(y1, 0.f), 256.f);
        x2 = fminf(fmaxf(x2, 0.f), 256.f);
        y2 = fminf(fmaxf(y2, 0.f), 256.f);
        if (x2 - x1 < 1.f) x2 = x1 + 1.f;
        if (y2 - y1 < 1.f) y2 = y1 + 1.f;
        bx[t][0] = x1; bx[t][1] = y1; bx[t][2] = x2; bx[t][3] = y2;
        keepsh[t] = 1.f;
    }
    __syncthreads();
    if (t < TOPK * TOPK) {
        int ii = t / TOPK, jj = t % TOPK;
        float xi1 = bx[ii][0], yi1 = bx[ii][1], xi2 = bx[ii][2], yi2 = bx[ii][3];
        float xj1 = bx[jj][0], yj1 = bx[jj][1], xj2 = bx[jj][2], yj2 = bx[jj][3];
        float ai = (xi2 - xi1) * (yi2 - yi1), aj = (xj2 - xj1) * (yj2 - yj1);
        float iw = fmaxf(fminf(xi2, xj2) - fmaxf(xi1, xj1), 0.f);
        float ih = fmaxf(fminf(yi2, yj2) - fmaxf(yi1, yj1), 0.f);
        float inter = iw * ih;
        iou[t] = inter / (ai + aj - inter);
    }
    __syncthreads();
    // parallel NMS: thread t owns box t; iteration order preserves serial semantics
    for (int iK = 0; iK < TOPK - 1; ++iK) {
        if (t > iK && t < TOPK) {
            if (keepsh[iK] > 0.5f && iou[iK * TOPK + t] > 0.85f) keepsh[t] = 0.f;
        }
        __syncthreads();
    }
    if (t < TOPK) {
        int rr = b * TOPK + t;
        rois[rr * 4 + 0] = bx[t][0]; rois[rr * 4 + 1] = bx[t][1];
        rois[rr * 4 + 2] = bx[t][2]; rois[rr * 4 + 3] = bx[t][3];
        valid[rr] = keepsh[t];
    }
}

// ---------------- roi-align, image-sliced (unchanged) ----------------
__global__ __launch_bounds__(256)
void align_img(const float* __restrict__ clip, const float* __restrict__ rois,
               float* __restrict__ pooled) {
    __shared__ float slice[16384];   // 64 KB: [pos 0..255][ch 0..63]
    int bid = blockIdx.x;            // 0..511
    int b = bid >> 4, cg = bid & 15;
    int t = threadIdx.x;
    for (int idx = t; idx < 16384; idx += 256) {
        int p = idx >> 6, c = idx & 63;
        slice[idx] = clip[(size_t)(1 + p) * 32768 + (size_t)b * 1024 + cg * 64 + c];
    }
    __syncthreads();
    int wv = t >> 6;
    int ch = t & 63;
    for (int rp = 0; rp < 8; ++rp) {
        int rl = rp * 4 + wv;
        if (rl >= TOPK) continue;
        int r = b * TOPK + rl;
        float rx1 = rois[r * 4 + 0] * 0.0625f, ry1 = rois[r * 4 + 1] * 0.0625f;
        float rw = fmaxf(rois[r * 4 + 2] * 0.0625f - rx1, 1.f);
        float rh = fmaxf(rois[r * 4 + 3] * 0.0625f - ry1, 1.f);
        float sx = rw / (float)POOLN, sy = rh / (float)POOLN;
        float acc = 0.f;
        for (int py = 0; py < POOLN; ++py) {
            float Y = ry1 + ((float)py + 0.5f) * sy;
            for (int px = 0; px < POOLN; ++px) {
                float Xx = rx1 + ((float)px + 0.5f) * sx;
                bool ok = (Y > -1.f) && (Y < 16.f) && (Xx > -1.f) && (Xx < 16.f);
                if (!ok) continue;
                float Xc = fminf(fmaxf(Xx, 0.f), 15.f);
                float Yc = fminf(fmaxf(Y, 0.f), 15.f);
                int x0 = (int)floorf(Xc), y0 = (int)floorf(Yc);
                int x1i = min(x0 + 1, 15), y1i = min(y0 + 1, 15);
                float lx = Xc - (float)x0, ly = Yc - (float)y0;
                float hx = 1.f - lx, hy = 1.f - ly;
                float w00 = hy * hx, w01 = hy * lx, w10 = ly * hx, w11 = ly * lx;
                float f00 = slice[(y0 * 16 + x0) * 64 + ch];
                float f01 = slice[(y0 * 16 + x1i) * 64 + ch];
                float f10 = slice[(y1i * 16 + x0) * 64 + ch];
                float f11 = slice[(y1i * 16 + x1i) * 64 + ch];
                acc += w00 * f00 + w01 * f01 + w10 * f10 + w11 * f11;
            }
        }
        pooled[(size_t)r * 1024 + cg * 64 + ch] = acc / 49.f;
    }
}

// ---------------- roi labels (unchanged) ----------------
__global__ __launch_bounds__(256)
void labels_k(const float* __restrict__ gt, const float* __restrict__ rois,
              float* __restrict__ labels) {
    __shared__ float red[4];
    int r = blockIdx.x, t = threadIdx.x;
    int b = r / TOPK;
    int x1 = min(max((int)rois[r * 4 + 0], 0), 256);
    int y1 = min(max((int)rois[r * 4 + 1], 0), 256);
    int x2 = min(max((int)rois[r * 4 + 2], 0), 256);
    int y2 = min(max((int)rois[r * 4 + 3], 0), 256);
    int cnt = (x2 - x1) * (y2 - y1);
    float s = 0.f;
    if (cnt > 0) {
        const float* g = gt + (size_t)b * (IMG * IMG);
        for (int yy = y1; yy < y2; ++yy) {
            const float* row = g + yy * IMG;
            for (int xx = x1 + t; xx < x2; xx += 256) s += row[xx];
        }
    }
    for (int off = 32; off; off >>= 1) s += __shfl_down(s, off);
    if ((t & 63) == 0) red[t >> 6] = s;
    __syncthreads();
    if (t == 0) {
        float tot = red[0] + red[1] + red[2] + red[3];
        labels[r] = (cnt > 0 && 2.f * tot > (float)cnt) ? 1.f : 0.f;
    }
}

// ---------------- fused fc1(relu) -> fc2 -> normalize, 4 rois/block ----------------
__global__ __launch_bounds__(256)
void fc_norm(const float* __restrict__ pooled, const float* __restrict__ w1T,
             const float* __restrict__ b1, const float* __restrict__ w2T,
             const float* __restrict__ b2, float* __restrict__ nf) {
    __shared__ float rows[4][1024];
    __shared__ float hsh[4][256];
    __shared__ float red[4];
    int r0 = blockIdx.x * 4, t = threadIdx.x;
    for (int q = 0; q < 4; ++q)
        for (int c = t; c < 1024; c += 256)
            rows[q][c] = pooled[(size_t)(r0 + q) * 1024 + c];
    __syncthreads();
    {
        float bv = b1[t];
        float acc[4] = {bv, bv, bv, bv};
        for (int c = 0; c < 1024; ++c) {
            float wv = w1T[c * 256 + t];
#pragma unroll
            for (int q = 0; q < 4; ++q) acc[q] = fmaf(rows[q][c], wv, acc[q]);
        }
#pragma unroll
        for (int q = 0; q < 4; ++q) hsh[q][t] = fmaxf(acc[q], 0.f);
    }
    __syncthreads();
    float pr[4];
    {
        float bv = b2[t];
        float acc[4] = {bv, bv, bv, bv};
        for (int c = 0; c < 256; ++c) {
            float wv = w2T[c * 256 + t];
#pragma unroll
            for (int q = 0; q < 4; ++q) acc[q] = fmaf(hsh[q][c], wv, acc[q]);
        }
#pragma unroll
        for (int q = 0; q < 4; ++q) pr[q] = acc[q];
    }
    for (int q = 0; q < 4; ++q) {
        float v = pr[q];
        float ss = v * v;
        for (int off = 32; off; off >>= 1) ss += __shfl_down(ss, off);
        if ((t & 63) == 0) red[t >> 6] = ss;
        __syncthreads();
        float tot = red[0] + red[1] + red[2] + red[3];
        float denom = fmaxf(sqrtf(tot), 1e-12f);
        nf[(size_t)(r0 + q) * 256 + t] = v / denom;
        __syncthreads();
    }
}

// ---------------- supcon, tiled outer-product (verified round-4 version) ----------------
__global__ __launch_bounds__(256)
void supcon_tile(const float* __restrict__ nf, const float* __restrict__ labels,
                 const float* __restrict__ valid, float* __restrict__ PS) {
    __shared__ __align__(16) float nfT[64 * 256];   // swizzled [j][c]
    __shared__ __align__(16) float myl[32 * 256];   // [i][c]
    __shared__ float labj[64], valj[64];
    int bid = blockIdx.x;
    int it = bid / SJT, jt = bid - it * SJT;
    int i0 = it * 32, j0 = jt * 64;
    int t = threadIdx.x;

    for (int idx = t; idx < 64 * 256; idx += 256) {
        int j = idx >> 8, c = idx & 255;
        float v = nf[(size_t)(j0 + j) * 256 + c];
        int byte_off = ((j << 10) + (c << 2)) ^ ((j & 7) << 4);
        *(float*)((char*)nfT + byte_off) = v;
    }
    for (int idx = t; idx < 32 * 256; idx += 256)
        myl[idx] = nf[(size_t)i0 * 256 + idx];
    if (t < 64) { labj[t] = labels[j0 + t]; valj[t] = valid[j0 + t]; }
    __syncthreads();

    int w = t >> 6, lane = t & 63;
    const char* jrow = (const char*)nfT + (lane << 10);
    const int sw = (lane & 7) << 4;
    const float* my0 = &myl[(w * 8) * 256];

    float d[8];
#pragma unroll
    for (int q = 0; q < 8; ++q) d[q] = 0.f;
    for (int c = 0; c < 256; c += 4) {
        float4 b4 = *(const float4*)(jrow + ((c << 2) ^ sw));
#pragma unroll
        for (int q = 0; q < 8; ++q) {
            float4 a4 = *(const float4*)(my0 + q * 256 + c);
            d[q] = fmaf(a4.x, b4.x, d[q]);
            d[q] = fmaf(a4.y, b4.y, d[q]);
            d[q] = fmaf(a4.z, b4.z, d[q]);
            d[q] = fmaf(a4.w, b4.w, d[q]);
        }
    }

    int jg = j0 + lane;
    float vj = valj[lane], lj = labj[lane];
#pragma unroll
    for (int q = 0; q < 8; ++q) {
        int ig = i0 + w * 8 + q;
        float vi = valid[ig];
        float li = labels[ig];
        bool vmask = (vi > 0.5f) && (vj > 0.5f) && (jg != ig);
        float e  = vmask ? expf(d[q] / 0.07f) : 0.f;
        bool pos = vmask && (lj == li);
        float ep  = pos ? e : 0.f;
        float npv = pos ? 1.f : 0.f;
        float sa = e, sp = ep, sn = npv;
#pragma unroll
        for (int off = 32; off; off >>= 1) {
            sa += __shfl_xor(sa, off);
            sp += __shfl_xor(sp, off);
            sn += __shfl_xor(sn, off);
        }
        if (lane == 0) {
            size_t o = ((size_t)ig * SJT + jt) * 3;
            PS[o + 0] = sa;
            PS[o + 1] = sp;
            PS[o + 2] = sn;
        }
    }
}

// ---------------- final: combine SJT tiles, per-row loss, mean ----------------
__global__ __launch_bounds__(256)
void final_reduce2(const float* __restrict__ PS, const float* __restrict__ valid,
                   float* __restrict__ out) {
    __shared__ float rl[4], ra[4];
    int t = threadIdx.x;
    float sl = 0.f, sc = 0.f;
    for (int i = t; i < NROI; i += 256) {
        float sa = 0.f, sp = 0.f, np = 0.f;
        for (int jt = 0; jt < SJT; ++jt) {
            size_t o = ((size_t)i * SJT + jt) * 3;
            sa += PS[o + 0];
            sp += PS[o + 1];
            np += PS[o + 2];
        }
        bool active = (valid[i] > 0.5f) && (np > 0.5f);
        float ratio = sp / (sa + 1e-12f);
        float l = -logf(ratio + 1e-12f);
        sl += active ? l : 0.f;
        sc += active ? 1.f : 0.f;
    }
    for (int off = 32; off; off >>= 1) { sl += __shfl_down(sl, off); sc += __shfl_down(sc, off); }
    if ((t & 63) == 0) { rl[t >> 6] = sl; ra[t >> 6] = sc; }
    __syncthreads();
    if (t == 0) {
        float L = rl[0] + rl[1] + rl[2] + rl[3];
        float A = ra[0] + ra[1] + ra[2] + ra[3];
        out[0] = (A > 0.f) ? (L / fmaxf(A, 1.f)) : 0.f;
    }
}

// ---------------- launch ----------------
extern "C" void kernel_launch(void* const* d_in, const int* in_sizes, int n_in,
                              void* d_out, int out_size, void* d_ws, size_t ws_size,
                              hipStream_t stream) {
    const float* clip   = (const float*)d_in[0];
    const float* gt     = (const float*)d_in[1];
    const float* conv_w = (const float*)d_in[2];
    const float* conv_b = (const float*)d_in[3];
    const float* cls_w  = (const float*)d_in[4];
    const float* cls_b  = (const float*)d_in[5];
    const float* reg_w  = (const float*)d_in[6];
    const float* reg_b  = (const float*)d_in[7];
    const float* w1     = (const float*)d_in[8];
    const float* b1     = (const float*)d_in[9];
    const float* w2     = (const float*)d_in[10];
    const float* b2     = (const float*)d_in[11];

    if (ws_size < WS_FLOATS * sizeof(float)) return;  // visible failure if ws too small

    float* ws  = (float*)d_ws;
    float* XP0 = ws + O_XP0;
    float* XP1 = ws + O_XP1;
    u16*   CH  = (u16*)(ws + O_CH);
    u16*   CL  = (u16*)(ws + O_CL);
    u16*   WHp = (u16*)(ws + O_WH);
    u16*   WLp = (u16*)(ws + O_WL);
    u16*   ZS  = (u16*)(ws + O_Z);
    float* HW  = ws + O_HW;
    float* SC  = ws + O_SC;
    float* RG  = ws + O_RG;
    float* ROI = ws + O_ROI;
    float* VAL = ws + O_VAL;
    float* LAB = ws + O_LAB;
    float* W1T = ws + O_W1T;
    float* W2T = ws + O_W2T;
    float* PO  = ws + O_PO;
    float* NF  = ws + O_NF;
    float* PS  = ws + O_PS;

    convert_all<<<NB_CLIP + NB_W + NB_Z + NB_HW + NB_W1T + NB_W2T, 256, 0, stream>>>(
        clip, conv_w, cls_w, reg_w, w1, w2, CH, CL, WHp, WLp, ZS, HW, W1T, W2T);
    conv_mfma<<<512, 256, 0, stream>>>(CH, CL, WHp, WLp, ZS, XP0, XP1);
    heads_kernel<<<NPOS / HB_POS, 256, 0, stream>>>(XP0, XP1, conv_b, HW, cls_b, reg_b, SC, RG);
    topk_nms<<<BATCH, 256, 0, stream>>>(SC, RG, ROI, VAL);
    align_img<<<512, 256, 0, stream>>>(clip, ROI, PO);
    labels_k<<<NROI, 256, 0, stream>>>(gt, ROI, LAB);
    fc_norm<<<NROI / 4, 256, 0, stream>>>(PO, W1T, b1, W2T, b2, NF);
    supcon_tile<<<30 * SJT, 256, 0, stream>>>(NF, LAB, VAL, PS);
    final_reduce2<<<1, 256, 0, stream>>>(PS, VAL, (float*)d_out);
}

// Round 6
// 561.677 us; speedup vs baseline: 1.3233x; 1.0734x over previous
//
#include <hip/hip_runtime.h>
#include <hip/hip_bf16.h>
#include <math.h>

typedef unsigned short u16;
typedef unsigned int u32;
typedef _Float16 f16;
typedef _Float16 f16x8 __attribute__((ext_vector_type(8)));
typedef float f32x4 __attribute__((ext_vector_type(4)));

// ---------------- constants ----------------
#define BATCH 32
#define CIN   1024
#define COUT  512
#define NPOS  8192
#define K9    9216
#define KHALF 4608
#define TOPK  30
#define NROI  960
#define POOLN 7
#define IMG   256
#define SJT   15      // supcon j-tiles of 64 (960/64)
#define HB_POS 32     // heads positions per block

// ---------------- ws layout (float units) ----------------
#define O_XP0  0ull
#define O_XP1  4194304ull
#define O_CH   8388608ull      // u16[8388608]
#define O_CL   12582912ull
#define O_WH   16777216ull     // u16[4718592]
#define O_WL   19136512ull
#define O_Z    21495808ull     // 512 u16 zeros
#define O_HW   21496064ull     // float[23040] head weights TRANSPOSED [a][c] (heads stages to LDS)
#define O_SC   21519104ull
#define O_RG   21592832ull
#define O_ROI  21887744ull
#define O_VAL  21891584ull
#define O_LAB  21892544ull
#define O_W1T  21893504ull     // float[262144] w1 transposed [c][o]
#define O_W2T  22155648ull     // float[65536]  w2 transposed [c][o]
#define WS_FLOATS 22221184ull
// overlays on XP0/XP1 region (used only after heads consumed XP0/XP1):
#define O_PO   0ull
#define O_NF   1474560ull
#define O_PS   1720320ull      // float[960][SJT][3] supcon partials (43200 floats)

// async global->LDS, 16 bytes/lane, LDS dest = wave-uniform base + lane*16
__device__ __forceinline__ void gl_lds16(const void* g, void* l) {
    __builtin_amdgcn_global_load_lds(
        (const __attribute__((address_space(1))) u32*)g,
        (__attribute__((address_space(3))) u32*)l,
        16, 0, 0);
}

// ---------------- fp16 hi/lo split ----------------
__device__ inline void split16(float x, u16& h, u16& l) {
    f16 hv = (f16)x;
    f16 lv = (f16)(x - (float)hv);
    h = *(u16*)&hv;
    l = *(u16*)&lv;
}

// ---------------- fused prep ----------------
#define NB_CLIP 8192
#define NB_W    2048
#define NB_Z    1
#define NB_HW   90
#define NB_W1T  1024
#define NB_W2T  256
__global__ __launch_bounds__(256)
void convert_all(const float* __restrict__ clip, const float* __restrict__ conv_w,
                 const float* __restrict__ cls_w, const float* __restrict__ reg_w,
                 const float* __restrict__ w1, const float* __restrict__ w2,
                 u16* __restrict__ CH, u16* __restrict__ CL,
                 u16* __restrict__ WH, u16* __restrict__ WL,
                 u16* __restrict__ Z, float* __restrict__ HW,
                 float* __restrict__ w1T, float* __restrict__ w2T) {
    __shared__ float wsh[2304];
    int bid = blockIdx.x, t = threadIdx.x;
    if (bid < NB_CLIP) {
        int tid = bid * 256 + t;
        int c4  = (tid & 255) * 4;
        int pos = (tid >> 8) & 255;
        int b   = tid >> 16;
        float4 v = *(const float4*)(clip + ((size_t)(1 + pos) * 32 + b) * 1024 + c4);
        float xs[4] = {v.x, v.y, v.z, v.w};
        ushort4 hh, ll;
        u16* hp = (u16*)&hh; u16* lp = (u16*)&ll;
#pragma unroll
        for (int q = 0; q < 4; ++q) split16(xs[q], hp[q], lp[q]);
        size_t o = ((size_t)(b * 256 + pos)) * 1024 + c4;
        *(ushort4*)(CH + o) = hh;
        *(ushort4*)(CL + o) = ll;
    } else if (bid < NB_CLIP + NB_W) {
        int bid2 = bid - NB_CLIP;
        int o = bid2 >> 2, cblk = bid2 & 3;
        const float* src = conv_w + (size_t)o * K9 + cblk * 2304;
        for (int i = t; i < 2304; i += 256) wsh[i] = src[i];
        __syncthreads();
#pragma unroll
        for (int p = 0; p < 9; ++p) {
            float x = wsh[t * 9 + p];
            u16 h, l;
            split16(x, h, l);
            size_t o2 = (size_t)o * K9 + p * 1024 + cblk * 256 + t;
            WH[o2] = h; WL[o2] = l;
        }
    } else if (bid < NB_CLIP + NB_W + NB_Z) {
        Z[t] = 0; Z[256 + t] = 0;
    } else if (bid < NB_CLIP + NB_W + NB_Z + NB_HW) {
        // head weights, transposed [a][c] (contiguous copy; heads stages to LDS coalesced)
        int tid2 = (bid - NB_CLIP - NB_W - NB_Z) * 256 + t;
        if (tid2 < 45 * 512) {
            int a = tid2 >> 9, c = tid2 & 511;
            HW[tid2] = (a < 9) ? cls_w[a * 512 + c] : reg_w[(a - 9) * 512 + c];
        }
    } else if (bid < NB_CLIP + NB_W + NB_Z + NB_HW + NB_W1T) {
        int tid2 = (bid - NB_CLIP - NB_W - NB_Z - NB_HW) * 256 + t;
        int o = tid2 >> 10, c = tid2 & 1023;
        w1T[c * 256 + o] = w1[(size_t)o * 1024 + c];
    } else {
        int tid2 = (bid - NB_CLIP - NB_W - NB_Z - NB_HW - NB_W1T) * 256 + t;
        int o = tid2 >> 8, c = tid2 & 255;
        w2T[c * 256 + o] = w2[(size_t)o * 256 + c];
    }
}

// ---------------- MFMA conv GEMM (verified round-0 version: 128x128, 2 blocks/CU) ----------------
__global__ __launch_bounds__(256, 2)
void conv_mfma(const u16* __restrict__ CH, const u16* __restrict__ CL,
               const u16* __restrict__ WH, const u16* __restrict__ WL,
               const u16* __restrict__ ZS,
               float* __restrict__ XP0, float* __restrict__ XP1) {
    __shared__ __align__(16) u16 Ah[8192];
    __shared__ __align__(16) u16 Al[8192];
    __shared__ __align__(16) u16 Bh[8192];
    __shared__ __align__(16) u16 Bl[8192];

    const int t = threadIdx.x;
    const int gid = blockIdx.x;
    const int nb = gid >> 7;
    const int g  = gid & 127;
    const int mb = g >> 1;
    const int ks = g & 1;
    const int ksOff = ks * KHALF;
    float* __restrict__ XP = ks ? XP1 : XP0;

    const int wave = t >> 6, lane = t & 63;

    int qA[2], siA[2], sjA[2], bA[2];
    const u16* srcBh[2];
    const u16* srcBl[2];
#pragma unroll
    for (int j = 0; j < 2; ++j) {
        int r = wave * 32 + j * 16 + (lane >> 2);
        int s = lane & 3;
        int q = s ^ ((r >> 1) & 3);
        qA[j] = q;
        int m = mb * 128 + r;
        bA[j] = m >> 8;
        int ij = m & 255;
        siA[j] = ij >> 4; sjA[j] = ij & 15;
        int o = nb * 128 + r;
        srcBh[j] = WH + (size_t)o * K9 + q * 8;
        srcBl[j] = WL + (size_t)o * K9 + q * 8;
    }

    const int wm = wave >> 1, wn = wave & 1;
    const int l16 = lane & 15, quad = lane >> 4;
    int offA[4], offB[4];
#pragma unroll
    for (int q = 0; q < 4; ++q) {
        int ar = wm * 64 + q * 16 + l16;
        offA[q] = ar * 32 + ((quad ^ ((ar >> 1) & 3)) << 3);
        int br = wn * 64 + q * 16 + l16;
        offB[q] = br * 32 + ((quad ^ ((br >> 1) & 3)) << 3);
    }

    f32x4 acc[4][4];
#pragma unroll
    for (int r = 0; r < 4; ++r)
#pragma unroll
        for (int c = 0; c < 4; ++c) acc[r][c] = (f32x4){0.f, 0.f, 0.f, 0.f};

    auto issue = [&](int it, int buf) {
        const int kg = ksOff + it * 32;
        const int p = kg >> 10;
        const int cb = kg & 1023;
        const int di = p / 3, dj = p - di * 3;
        const int base = buf << 12;
#pragma unroll
        for (int j = 0; j < 2; ++j) {
            int ii = siA[j] + di - 1, jj = sjA[j] + dj - 1;
            bool ok = ((unsigned)ii < 16u) && ((unsigned)jj < 16u);
            size_t aoff = ok ? ((((size_t)bA[j] << 8) + (size_t)(ii * 16 + jj)) << 10) + cb + qA[j] * 8
                             : 0;
            const u16* gah = ok ? CH + aoff : ZS;
            const u16* gal = ok ? CL + aoff : ZS;
            int lb = base + wave * 1024 + j * 512;
            gl_lds16(gah,           &Ah[lb]);
            gl_lds16(gal,           &Al[lb]);
            gl_lds16(srcBh[j] + kg, &Bh[lb]);
            gl_lds16(srcBl[j] + kg, &Bl[lb]);
        }
    };

    issue(0, 0);
    for (int it = 0; it < 144; ++it) {
        const int cur = it & 1;
        __syncthreads();
        if (it + 1 < 144) issue(it + 1, cur ^ 1);

        const int fb = cur << 12;
        f16x8 fah[4], fal[4], fbh[4], fbl[4];
#pragma unroll
        for (int x = 0; x < 4; ++x) {
            fah[x] = *(const f16x8*)&Ah[fb + offA[x]];
            fal[x] = *(const f16x8*)&Al[fb + offA[x]];
            fbh[x] = *(const f16x8*)&Bh[fb + offB[x]];
            fbl[x] = *(const f16x8*)&Bl[fb + offB[x]];
        }
#pragma unroll
        for (int tm = 0; tm < 4; ++tm)
#pragma unroll
            for (int tn = 0; tn < 4; ++tn) {
                acc[tm][tn] = __builtin_amdgcn_mfma_f32_16x16x32_f16(fal[tm], fbh[tn], acc[tm][tn], 0, 0, 0);
                acc[tm][tn] = __builtin_amdgcn_mfma_f32_16x16x32_f16(fah[tm], fbl[tn], acc[tm][tn], 0, 0, 0);
                acc[tm][tn] = __builtin_amdgcn_mfma_f32_16x16x32_f16(fah[tm], fbh[tn], acc[tm][tn], 0, 0, 0);
            }
    }

#pragma unroll
    for (int tm = 0; tm < 4; ++tm) {
        int mbase = mb * 128 + wm * 64 + tm * 16 + quad * 4;
#pragma unroll
        for (int tn = 0; tn < 4; ++tn) {
            int o = nb * 128 + wn * 64 + tn * 16 + l16;
#pragma unroll
            for (int r = 0; r < 4; ++r)
                XP[(size_t)(mbase + r) * COUT + o] = acc[tm][tn][r];
        }
    }
}

// ---------------- heads v2 (verified round-5 version) ----------------
__global__ __launch_bounds__(256)
void heads_kernel(const float* __restrict__ XP0, const float* __restrict__ XP1,
                  const float* __restrict__ conv_b, const float* __restrict__ HWT,
                  const float* __restrict__ cls_b, const float* __restrict__ reg_b,
                  float* __restrict__ scores, float* __restrict__ regs) {
    __shared__ __align__(16) float Xs[HB_POS * 512];   // swizzled [pos][c], 64 KB
    __shared__ __align__(16) float Ws[45 * 512];       // [a][c], 90 KB
    int t = threadIdx.x;
    int mm0 = blockIdx.x * HB_POS;

    for (int idx = t; idx < HB_POS * 128; idx += 256) {
        int p = idx >> 7, cq = idx & 127;
        int mm = mm0 + p;
        float4 a = *(const float4*)(XP0 + (size_t)mm * COUT + cq * 4);
        float4 b = *(const float4*)(XP1 + (size_t)mm * COUT + cq * 4);
        float4 cv = *(const float4*)(conv_b + cq * 4);
        float4 r;
        r.x = fmaxf(a.x + b.x + cv.x, 0.f);
        r.y = fmaxf(a.y + b.y + cv.y, 0.f);
        r.z = fmaxf(a.z + b.z + cv.z, 0.f);
        r.w = fmaxf(a.w + b.w + cv.w, 0.f);
        int byte_off = ((p << 11) + (cq << 4)) ^ ((p & 7) << 4);
        *(float4*)((char*)Xs + byte_off) = r;
    }
    for (int idx = t; idx < 5760; idx += 256)
        ((float4*)Ws)[idx] = ((const float4*)HWT)[idx];
    __syncthreads();

    int w = t >> 6, lane = t & 63;
    int p = lane & 31, half = lane >> 5;
    const char* xrow = (const char*)Xs + (p << 11) + (half << 10);
    const int swz = (p & 7) << 4;
    int a0 = w * 12;
    const float* wrow[12];
#pragma unroll
    for (int k = 0; k < 12; ++k) {
        int ak = a0 + k; if (ak > 44) ak = 44;
        wrow[k] = Ws + ak * 512 + half * 256;
    }

    float acc[12];
#pragma unroll
    for (int k = 0; k < 12; ++k) acc[k] = 0.f;
    for (int cq = 0; cq < 64; ++cq) {
        float4 x4 = *(const float4*)(xrow + ((cq << 4) ^ swz));
#pragma unroll
        for (int k = 0; k < 12; ++k) {
            float4 w4 = *(const float4*)(wrow[k] + cq * 4);
            acc[k] = fmaf(x4.x, w4.x, acc[k]);
            acc[k] = fmaf(x4.y, w4.y, acc[k]);
            acc[k] = fmaf(x4.z, w4.z, acc[k]);
            acc[k] = fmaf(x4.w, w4.w, acc[k]);
        }
    }
#pragma unroll
    for (int k = 0; k < 12; ++k) acc[k] += __shfl_xor(acc[k], 32);

    if (half == 0) {
        int mm = mm0 + p;
        int b = mm >> 8, cell = mm & 255;
#pragma unroll
        for (int k = 0; k < 12; ++k) {
            int a = a0 + k;
            if (a < 45) {
                if (a < 9) {
                    float v = acc[k] + cls_b[a];
                    scores[(size_t)b * 2304 + cell * 9 + a] = 1.f / (1.f + expf(-v));
                } else {
                    int ch = a - 9;
                    float v = acc[k] + reg_b[ch];
                    regs[((size_t)b * 2304 + cell * 9 + (ch >> 2)) * 4 + (ch & 3)] = v;
                }
            }
        }
    }
}

// ---------------- top-k + decode + NMS (register-resident scores, 1 barrier/iter) ----------------
__global__ __launch_bounds__(256)
void topk_nms(const float* __restrict__ scores, const float* __restrict__ regs,
              float* __restrict__ rois, float* __restrict__ valid) {
    __shared__ float wv[2][4];
    __shared__ int   wi[2][4];
    __shared__ int   sel[TOPK];
    __shared__ float bx[TOPK][4];
    __shared__ float iou[TOPK * TOPK];
    __shared__ float keepsh[TOPK];
    int b = blockIdx.x, t = threadIdx.x;
    int lane = t & 63, w = t >> 6;
    // scores live in registers: thread t owns indices t*9 .. t*9+8 (2304 = 256*9)
    float v[9];
#pragma unroll
    for (int q = 0; q < 9; ++q) v[q] = scores[(size_t)b * 2304 + t * 9 + q];

    for (int k = 0; k < TOPK; ++k) {
        int kb = k & 1;
        float bv = -1e30f; int bi = 1 << 30;
#pragma unroll
        for (int q = 0; q < 9; ++q) {
            int idx = t * 9 + q;
            if (v[q] > bv || (v[q] == bv && idx < bi)) { bv = v[q]; bi = idx; }
        }
        for (int off = 32; off; off >>= 1) {
            float ov = __shfl_down(bv, off);
            int   oi = __shfl_down(bi, off);
            if (ov > bv || (ov == bv && oi < bi)) { bv = ov; bi = oi; }
        }
        if (lane == 0) { wv[kb][w] = bv; wi[kb][w] = bi; }
        __syncthreads();   // wv[kb] ready; double-buffer so no trailing barrier needed
        float fv = wv[kb][0]; int fi = wi[kb][0];
#pragma unroll
        for (int q2 = 1; q2 < 4; ++q2)
            if (wv[kb][q2] > fv || (wv[kb][q2] == fv && wi[kb][q2] < fi)) { fv = wv[kb][q2]; fi = wi[kb][q2]; }
        if (t == 0) sel[k] = fi;
        // unique owner clears its register copy (unrolled: compile-time indices only)
#pragma unroll
        for (int q = 0; q < 9; ++q)
            if (t * 9 + q == fi) v[q] = -1e38f;
    }
    __syncthreads();   // sel[] visible

    if (t < TOPK) {
        int n = sel[t];
        int cell = n / 9, a = n % 9;
        int ci = cell >> 4, cj = cell & 15;
        int siid = a / 3, riid = a % 3;
        const double scl[3] = {8.0, 16.0, 32.0};
        const double rat[3] = {0.5, 1.0, 2.0};
        double s = scl[siid], r = rat[riid];
        double wD = s * sqrt(r), hD = s / sqrt(r);
        double xc = (cj + 0.5) * 16.0, yc = (ci + 0.5) * 16.0;
        float ax1 = (float)(xc - wD / 2), ay1 = (float)(yc - hD / 2);
        float ax2 = (float)(xc + wD / 2), ay2 = (float)(yc + hD / 2);
        float aw = ax2 - ax1, ah = ay2 - ay1;
        float ctrx = ax1 + 0.5f * aw, ctry = ay1 + 0.5f * ah;
        const float* rg = regs + ((size_t)b * 2304 + n) * 4;
        float cx = rg[0] * aw + ctrx;
        float cy = rg[1] * ah + ctry;
        float pw = expf(rg[2]) * aw;
        float ph = expf(rg[3]) * ah;
        float x1 = cx - 0.5f * pw, y1 = cy - 0.5f * ph;
        float x2 = cx + 0.5f * pw, y2 = cy + 0.5f * ph;
        x1 = fminf(fmaxf(x1, 0.f), 256.f);
        y1 = fminf(fmaxf(y1, 0.f), 256.f);
        x2 = fminf(fmaxf(x2, 0.f), 256.f);
        y2 = fminf(fmaxf(y2, 0.f), 256.f);
        if (x2 - x1 < 1.f) x2 = x1 + 1.f;
        if (y2 - y1 < 1.f) y2 = y1 + 1.f;
        bx[t][0] = x1; bx[t][1] = y1; bx[t][2] = x2; bx[t][3] = y2;
        keepsh[t] = 1.f;
    }
    __syncthreads();
    if (t < TOPK * TOPK) {
        int ii = t / TOPK, jj = t % TOPK;
        float xi1 = bx[ii][0], yi1 = bx[ii][1], xi2 = bx[ii][2], yi2 = bx[ii][3];
        float xj1 = bx[jj][0], yj1 = bx[jj][1], xj2 = bx[jj][2], yj2 = bx[jj][3];
        float ai = (xi2 - xi1) * (yi2 - yi1), aj = (xj2 - xj1) * (yj2 - yj1);
        float iw = fmaxf(fminf(xi2, xj2) - fmaxf(xi1, xj1), 0.f);
        float ih = fmaxf(fminf(yi2, yj2) - fmaxf(yi1, yj1), 0.f);
        float inter = iw * ih;
        iou[t] = inter / (ai + aj - inter);
    }
    __syncthreads();
    // parallel NMS: thread t owns box t; iteration order preserves serial semantics
    for (int iK = 0; iK < TOPK - 1; ++iK) {
        if (t > iK && t < TOPK) {
            if (keepsh[iK] > 0.5f && iou[iK * TOPK + t] > 0.85f) keepsh[t] = 0.f;
        }
        __syncthreads();
    }
    if (t < TOPK) {
        int rr = b * TOPK + t;
        rois[rr * 4 + 0] = bx[t][0]; rois[rr * 4 + 1] = bx[t][1];
        rois[rr * 4 + 2] = bx[t][2]; rois[rr * 4 + 3] = bx[t][3];
        valid[rr] = keepsh[t];
    }
}

// ---------------- fused roi-align + roi-labels (both depend only on topk outputs) ----------------
__global__ __launch_bounds__(256)
void roi_post(const float* __restrict__ clip, const float* __restrict__ rois,
              float* __restrict__ pooled,
              const float* __restrict__ gt, float* __restrict__ labels) {
    __shared__ float slice[16384];   // 64 KB (align part); labels part uses first 4 floats
    int bid = blockIdx.x;
    int t = threadIdx.x;
    if (bid < 512) {
        // ---- align_img body (unchanged) ----
        int b = bid >> 4, cg = bid & 15;
        for (int idx = t; idx < 16384; idx += 256) {
            int p = idx >> 6, c = idx & 63;
            slice[idx] = clip[(size_t)(1 + p) * 32768 + (size_t)b * 1024 + cg * 64 + c];
        }
        __syncthreads();
        int wv = t >> 6;
        int ch = t & 63;
        for (int rp = 0; rp < 8; ++rp) {
            int rl = rp * 4 + wv;
            if (rl >= TOPK) continue;
            int r = b * TOPK + rl;
            float rx1 = rois[r * 4 + 0] * 0.0625f, ry1 = rois[r * 4 + 1] * 0.0625f;
            float rw = fmaxf(rois[r * 4 + 2] * 0.0625f - rx1, 1.f);
            float rh = fmaxf(rois[r * 4 + 3] * 0.0625f - ry1, 1.f);
            float sx = rw / (float)POOLN, sy = rh / (float)POOLN;
            float acc = 0.f;
            for (int py = 0; py < POOLN; ++py) {
                float Y = ry1 + ((float)py + 0.5f) * sy;
                for (int px = 0; px < POOLN; ++px) {
                    float Xx = rx1 + ((float)px + 0.5f) * sx;
                    bool ok = (Y > -1.f) && (Y < 16.f) && (Xx > -1.f) && (Xx < 16.f);
                    if (!ok) continue;
                    float Xc = fminf(fmaxf(Xx, 0.f), 15.f);
                    float Yc = fminf(fmaxf(Y, 0.f), 15.f);
                    int x0 = (int)floorf(Xc), y0 = (int)floorf(Yc);
                    int x1i = min(x0 + 1, 15), y1i = min(y0 + 1, 15);
                    float lx = Xc - (float)x0, ly = Yc - (float)y0;
                    float hx = 1.f - lx, hy = 1.f - ly;
                    float w00 = hy * hx, w01 = hy * lx, w10 = ly * hx, w11 = ly * lx;
                    float f00 = slice[(y0 * 16 + x0) * 64 + ch];
                    float f01 = slice[(y0 * 16 + x1i) * 64 + ch];
                    float f10 = slice[(y1i * 16 + x0) * 64 + ch];
                    float f11 = slice[(y1i * 16 + x1i) * 64 + ch];
                    acc += w00 * f00 + w01 * f01 + w10 * f10 + w11 * f11;
                }
            }
            pooled[(size_t)r * 1024 + cg * 64 + ch] = acc / 49.f;
        }
    } else {
        // ---- labels_k body (unchanged math) ----
        int r = bid - 512;
        int b = r / TOPK;
        int x1 = min(max((int)rois[r * 4 + 0], 0), 256);
        int y1 = min(max((int)rois[r * 4 + 1], 0), 256);
        int x2 = min(max((int)rois[r * 4 + 2], 0), 256);
        int y2 = min(max((int)rois[r * 4 + 3], 0), 256);
        int cnt = (x2 - x1) * (y2 - y1);
        float s = 0.f;
        if (cnt > 0) {
            const float* g = gt + (size_t)b * (IMG * IMG);
            for (int yy = y1; yy < y2; ++yy) {
                const float* row = g + yy * IMG;
                for (int xx = x1 + t; xx < x2; xx += 256) s += row[xx];
            }
        }
        for (int off = 32; off; off >>= 1) s += __shfl_down(s, off);
        if ((t & 63) == 0) slice[t >> 6] = s;
        __syncthreads();
        if (t == 0) {
            float tot = slice[0] + slice[1] + slice[2] + slice[3];
            labels[r] = (cnt > 0 && 2.f * tot > (float)cnt) ? 1.f : 0.f;
        }
    }
}

// ---------------- fused fc1(relu) -> fc2 -> normalize, b128 uniform X reads ----------------
__global__ __launch_bounds__(256)
void fc_norm(const float* __restrict__ pooled, const float* __restrict__ w1T,
             const float* __restrict__ b1, const float* __restrict__ w2T,
             const float* __restrict__ b2, float* __restrict__ nf) {
    __shared__ __align__(16) float rows[4][1024];
    __shared__ __align__(16) float hsh[4][256];
    __shared__ float red[4];
    int r0 = blockIdx.x * 4, t = threadIdx.x;
#pragma unroll
    for (int q = 0; q < 4; ++q)
        *(float4*)&rows[q][t * 4] = *(const float4*)(pooled + (size_t)(r0 + q) * 1024 + t * 4);
    __syncthreads();
    {
        float bv = b1[t];
        float acc[4] = {bv, bv, bv, bv};
        for (int c = 0; c < 1024; c += 4) {
            float w0 = w1T[(c + 0) * 256 + t];
            float w1v = w1T[(c + 1) * 256 + t];
            float w2v = w1T[(c + 2) * 256 + t];
            float w3v = w1T[(c + 3) * 256 + t];
#pragma unroll
            for (int q = 0; q < 4; ++q) {
                float4 x4 = *(const float4*)&rows[q][c];
                acc[q] = fmaf(x4.x, w0, acc[q]);
                acc[q] = fmaf(x4.y, w1v, acc[q]);
                acc[q] = fmaf(x4.z, w2v, acc[q]);
                acc[q] = fmaf(x4.w, w3v, acc[q]);
            }
        }
#pragma unroll
        for (int q = 0; q < 4; ++q) hsh[q][t] = fmaxf(acc[q], 0.f);
    }
    __syncthreads();
    float pr[4];
    {
        float bv = b2[t];
        float acc[4] = {bv, bv, bv, bv};
        for (int c = 0; c < 256; c += 4) {
            float w0 = w2T[(c + 0) * 256 + t];
            float w1v = w2T[(c + 1) * 256 + t];
            float w2v = w2T[(c + 2) * 256 + t];
            float w3v = w2T[(c + 3) * 256 + t];
#pragma unroll
            for (int q = 0; q < 4; ++q) {
                float4 x4 = *(const float4*)&hsh[q][c];
                acc[q] = fmaf(x4.x, w0, acc[q]);
                acc[q] = fmaf(x4.y, w1v, acc[q]);
                acc[q] = fmaf(x4.z, w2v, acc[q]);
                acc[q] = fmaf(x4.w, w3v, acc[q]);
            }
        }
#pragma unroll
        for (int q = 0; q < 4; ++q) pr[q] = acc[q];
    }
    for (int q = 0; q < 4; ++q) {
        float v = pr[q];
        float ss = v * v;
        for (int off = 32; off; off >>= 1) ss += __shfl_down(ss, off);
        if ((t & 63) == 0) red[t >> 6] = ss;
        __syncthreads();
        float tot = red[0] + red[1] + red[2] + red[3];
        float denom = fmaxf(sqrtf(tot), 1e-12f);
        nf[(size_t)(r0 + q) * 256 + t] = v / denom;
        __syncthreads();
    }
}

// ---------------- supcon, tiled outer-product (verified round-4 version) ----------------
__global__ __launch_bounds__(256)
void supcon_tile(const float* __restrict__ nf, const float* __restrict__ labels,
                 const float* __restrict__ valid, float* __restrict__ PS) {
    __shared__ __align__(16) float nfT[64 * 256];   // swizzled [j][c]
    __shared__ __align__(16) float myl[32 * 256];   // [i][c]
    __shared__ float labj[64], valj[64];
    int bid = blockIdx.x;
    int it = bid / SJT, jt = bid - it * SJT;
    int i0 = it * 32, j0 = jt * 64;
    int t = threadIdx.x;

    for (int idx = t; idx < 64 * 256; idx += 256) {
        int j = idx >> 8, c = idx & 255;
        float v = nf[(size_t)(j0 + j) * 256 + c];
        int byte_off = ((j << 10) + (c << 2)) ^ ((j & 7) << 4);
        *(float*)((char*)nfT + byte_off) = v;
    }
    for (int idx = t; idx < 32 * 256; idx += 256)
        myl[idx] = nf[(size_t)i0 * 256 + idx];
    if (t < 64) { labj[t] = labels[j0 + t]; valj[t] = valid[j0 + t]; }
    __syncthreads();

    int w = t >> 6, lane = t & 63;
    const char* jrow = (const char*)nfT + (lane << 10);
    const int sw = (lane & 7) << 4;
    const float* my0 = &myl[(w * 8) * 256];

    float d[8];
#pragma unroll
    for (int q = 0; q < 8; ++q) d[q] = 0.f;
    for (int c = 0; c < 256; c += 4) {
        float4 b4 = *(const float4*)(jrow + ((c << 2) ^ sw));
#pragma unroll
        for (int q = 0; q < 8; ++q) {
            float4 a4 = *(const float4*)(my0 + q * 256 + c);
            d[q] = fmaf(a4.x, b4.x, d[q]);
            d[q] = fmaf(a4.y, b4.y, d[q]);
            d[q] = fmaf(a4.z, b4.z, d[q]);
            d[q] = fmaf(a4.w, b4.w, d[q]);
        }
    }

    int jg = j0 + lane;
    float vj = valj[lane], lj = labj[lane];
#pragma unroll
    for (int q = 0; q < 8; ++q) {
        int ig = i0 + w * 8 + q;
        float vi = valid[ig];
        float li = labels[ig];
        bool vmask = (vi > 0.5f) && (vj > 0.5f) && (jg != ig);
        float e  = vmask ? expf(d[q] / 0.07f) : 0.f;
        bool pos = vmask && (lj == li);
        float ep  = pos ? e : 0.f;
        float npv = pos ? 1.f : 0.f;
        float sa = e, sp = ep, sn = npv;
#pragma unroll
        for (int off = 32; off; off >>= 1) {
            sa += __shfl_xor(sa, off);
            sp += __shfl_xor(sp, off);
            sn += __shfl_xor(sn, off);
        }
        if (lane == 0) {
            size_t o = ((size_t)ig * SJT + jt) * 3;
            PS[o + 0] = sa;
            PS[o + 1] = sp;
            PS[o + 2] = sn;
        }
    }
}

// ---------------- final: combine SJT tiles, per-row loss, mean ----------------
__global__ __launch_bounds__(256)
void final_reduce2(const float* __restrict__ PS, const float* __restrict__ valid,
                   float* __restrict__ out) {
    __shared__ float rl[4], ra[4];
    int t = threadIdx.x;
    float sl = 0.f, sc = 0.f;
    for (int i = t; i < NROI; i += 256) {
        float sa = 0.f, sp = 0.f, np = 0.f;
        for (int jt = 0; jt < SJT; ++jt) {
            size_t o = ((size_t)i * SJT + jt) * 3;
            sa += PS[o + 0];
            sp += PS[o + 1];
            np += PS[o + 2];
        }
        bool active = (valid[i] > 0.5f) && (np > 0.5f);
        float ratio = sp / (sa + 1e-12f);
        float l = -logf(ratio + 1e-12f);
        sl += active ? l : 0.f;
        sc += active ? 1.f : 0.f;
    }
    for (int off = 32; off; off >>= 1) { sl += __shfl_down(sl, off); sc += __shfl_down(sc, off); }
    if ((t & 63) == 0) { rl[t >> 6] = sl; ra[t >> 6] = sc; }
    __syncthreads();
    if (t == 0) {
        float L = rl[0] + rl[1] + rl[2] + rl[3];
        float A = ra[0] + ra[1] + ra[2] + ra[3];
        out[0] = (A > 0.f) ? (L / fmaxf(A, 1.f)) : 0.f;
    }
}

// ---------------- launch ----------------
extern "C" void kernel_launch(void* const* d_in, const int* in_sizes, int n_in,
                              void* d_out, int out_size, void* d_ws, size_t ws_size,
                              hipStream_t stream) {
    const float* clip   = (const float*)d_in[0];
    const float* gt     = (const float*)d_in[1];
    const float* conv_w = (const float*)d_in[2];
    const float* conv_b = (const float*)d_in[3];
    const float* cls_w  = (const float*)d_in[4];
    const float* cls_b  = (const float*)d_in[5];
    const float* reg_w  = (const float*)d_in[6];
    const float* reg_b  = (const float*)d_in[7];
    const float* w1     = (const float*)d_in[8];
    const float* b1     = (const float*)d_in[9];
    const float* w2     = (const float*)d_in[10];
    const float* b2     = (const float*)d_in[11];

    if (ws_size < WS_FLOATS * sizeof(float)) return;  // visible failure if ws too small

    float* ws  = (float*)d_ws;
    float* XP0 = ws + O_XP0;
    float* XP1 = ws + O_XP1;
    u16*   CH  = (u16*)(ws + O_CH);
    u16*   CL  = (u16*)(ws + O_CL);
    u16*   WHp = (u16*)(ws + O_WH);
    u16*   WLp = (u16*)(ws + O_WL);
    u16*   ZS  = (u16*)(ws + O_Z);
    float* HW  = ws + O_HW;
    float* SC  = ws + O_SC;
    float* RG  = ws + O_RG;
    float* ROI = ws + O_ROI;
    float* VAL = ws + O_VAL;
    float* LAB = ws + O_LAB;
    float* W1T = ws + O_W1T;
    float* W2T = ws + O_W2T;
    float* PO  = ws + O_PO;
    float* NF  = ws + O_NF;
    float* PS  = ws + O_PS;

    convert_all<<<NB_CLIP + NB_W + NB_Z + NB_HW + NB_W1T + NB_W2T, 256, 0, stream>>>(
        clip, conv_w, cls_w, reg_w, w1, w2, CH, CL, WHp, WLp, ZS, HW, W1T, W2T);
    conv_mfma<<<512, 256, 0, stream>>>(CH, CL, WHp, WLp, ZS, XP0, XP1);
    heads_kernel<<<NPOS / HB_POS, 256, 0, stream>>>(XP0, XP1, conv_b, HW, cls_b, reg_b, SC, RG);
    topk_nms<<<BATCH, 256, 0, stream>>>(SC, RG, ROI, VAL);
    roi_post<<<512 + NROI, 256, 0, stream>>>(clip, ROI, PO, gt, LAB);
    fc_norm<<<NROI / 4, 256, 0, stream>>>(PO, W1T, b1, W2T, b2, NF);
    supcon_tile<<<30 * SJT, 256, 0, stream>>>(NF, LAB, VAL, PS);
    final_reduce2<<<1, 256, 0, stream>>>(PS, VAL, (float*)d_out);
}